// Round 2
// baseline (4800.960 us; speedup 1.0000x reference)
//
#include <hip/hip_runtime.h>
#include <cstdint>
#include <cstddef>

#define N_NODES 50000
#define N_EDGES 200000
#define N_GRAPHS 2000
#define F_IN 373
#define NEG_SLOPE 0.2f
#define BN_EPS 1e-5f

static inline int cdiv(long long a, long long b) { return (int)((a + b - 1) / b); }

__device__ __forceinline__ float lrelu(float x) { return x > 0.f ? x : NEG_SLOPE * x; }

__device__ __forceinline__ void atomAddF(float* p, float v) {
#if defined(__HIP_DEVICE_COMPILE__)
  unsafeAtomicAdd(p, v);  // native global_atomic_add_f32 on gfx950
#else
  atomicAdd(p, v);
#endif
}

// monotone float<->uint encoding for atomicMax on floats
__device__ __forceinline__ unsigned fenc(float x) {
  unsigned u = __float_as_uint(x);
  return (u & 0x80000000u) ? ~u : (u | 0x80000000u);
}
__device__ __forceinline__ float fdec(unsigned u) {
  unsigned b = (u & 0x80000000u) ? (u & 0x7fffffffu) : ~u;
  return __uint_as_float(b);
}

// ---------------- utility ----------------
__global__ void k_zero(float* p, long long n) {
  long long i = (long long)blockIdx.x * blockDim.x + threadIdx.x;
  if (i < n) p[i] = 0.f;
}
__global__ void k_fill1(float* p, int n) {
  int i = blockIdx.x * blockDim.x + threadIdx.x;
  if (i < n) p[i] = 1.0f;
}
__global__ void k_deg_accum(float* deg, const int* __restrict__ dst, int e) {
  int i = blockIdx.x * blockDim.x + threadIdx.x;
  if (i < e) atomAddF(&deg[dst[i]], 1.0f);
}
__global__ void k_dinv(float* deg, int n) {
  int i = blockIdx.x * blockDim.x + threadIdx.x;
  if (i < n) deg[i] = rsqrtf(deg[i]);
}

// -------- GEMM: C[M, col] = A[M,K] @ W[K, col0+col], col<Nsub --------
// flags: 1=bias, 2=relu
__global__ __launch_bounds__(256) void k_gemm(
    const float* __restrict__ A, const float* __restrict__ W,
    const float* __restrict__ bias, float* __restrict__ C,
    int M, int K, int Nsub, int ldW, int ldC, int col0, int flags) {
  __shared__ float As[16][68];
  __shared__ float Bs[16][68];
  const int bm = blockIdx.y * 64;
  const int bn = blockIdx.x * 64;
  const int tid = threadIdx.x;
  const int tm = (tid >> 4) << 2;
  const int tn = (tid & 15) << 2;
  float acc[4][4] = {};
  for (int k0 = 0; k0 < K; k0 += 16) {
    {
      int idx = tid * 4;
      int row = idx >> 4;   // 0..63
      int kk = idx & 15;    // 0,4,8,12
      const float* ap = A + (size_t)(bm + row) * K + k0 + kk;
      bool rok = (bm + row) < M;
#pragma unroll
      for (int i = 0; i < 4; i++) {
        int kcur = k0 + kk + i;
        As[kk + i][row] = (rok && kcur < K) ? ap[i] : 0.f;
      }
    }
#pragma unroll
    for (int i = 0; i < 4; i++) {
      int idx = tid + i * 256;
      int kk = idx >> 6;
      int nn = idx & 63;
      int kcur = k0 + kk;
      Bs[kk][nn] = (kcur < K && (bn + nn) < Nsub)
                       ? W[(size_t)kcur * ldW + col0 + bn + nn] : 0.f;
    }
    __syncthreads();
#pragma unroll
    for (int kk = 0; kk < 16; kk++) {
      float av[4], bv[4];
#pragma unroll
      for (int i = 0; i < 4; i++) av[i] = As[kk][tm + i];
#pragma unroll
      for (int j = 0; j < 4; j++) bv[j] = Bs[kk][tn + j];
#pragma unroll
      for (int i = 0; i < 4; i++)
#pragma unroll
        for (int j = 0; j < 4; j++) acc[i][j] += av[i] * bv[j];
    }
    __syncthreads();
  }
#pragma unroll
  for (int i = 0; i < 4; i++) {
    int row = bm + tm + i;
    if (row >= M) continue;
#pragma unroll
    for (int j = 0; j < 4; j++) {
      int col = bn + tn + j;
      if (col >= Nsub) continue;
      float v = acc[i][j];
      if (flags & 1) v += bias[col0 + col];
      if (flags & 2) v = fmaxf(v, 0.f);
      C[(size_t)row * ldC + col] = v;
    }
  }
}

// ---------------- GCN ----------------
__global__ void k_gcn_init(float* __restrict__ out, const float* __restrict__ h,
                           const float* __restrict__ dinv, const float* __restrict__ bias,
                           int n, int F) {
  long long idx = (long long)blockIdx.x * blockDim.x + threadIdx.x;
  if (idx >= (long long)n * F) return;
  int node = (int)(idx / F);
  int f = (int)(idx % F);
  float di = dinv[node];
  out[idx] = di * di * h[idx] + bias[f];
}
__global__ void k_gcn_edge(float* __restrict__ out, const float* __restrict__ h,
                           const float* __restrict__ dinv, const int* __restrict__ src,
                           const int* __restrict__ dst, int e, int F) {
  long long idx = (long long)blockIdx.x * blockDim.x + threadIdx.x;
  if (idx >= (long long)e * F) return;
  int ed = (int)(idx / F);
  int f = (int)(idx % F);
  int s = src[ed], d = dst[ed];
  atomAddF(&out[(size_t)d * F + f], dinv[s] * dinv[d] * h[(size_t)s * F + f]);
}
__global__ void k_relu_bn(float* __restrict__ X, const float* __restrict__ g,
                          const float* __restrict__ b, const float* __restrict__ m,
                          const float* __restrict__ v, int n, int F) {
  long long idx = (long long)blockIdx.x * blockDim.x + threadIdx.x;
  if (idx >= (long long)n * F) return;
  int f = (int)(idx % F);
  float val = fmaxf(X[idx], 0.f);
  X[idx] = (val - m[f]) * rsqrtf(v[f] + BN_EPS) * g[f] + b[f];
}

// ---------------- GAT (single-head kernels) ----------------
__global__ void k_logits1(const float* __restrict__ h, int ldH,
                          const float* __restrict__ a_s, const float* __restrict__ a_d,
                          float* __restrict__ als, float* __restrict__ ald, int n, int C) {
  int wid = (blockIdx.x * blockDim.x + threadIdx.x) >> 6;
  int lane = threadIdx.x & 63;
  if (wid >= n) return;
  const float* hp = h + (size_t)wid * ldH;
  float ss = 0.f, sd = 0.f;
  for (int c = lane; c < C; c += 64) {
    float hv = hp[c];
    ss += hv * a_s[c];
    sd += hv * a_d[c];
  }
#pragma unroll
  for (int off = 32; off > 0; off >>= 1) {
    ss += __shfl_down(ss, off);
    sd += __shfl_down(sd, off);
  }
  if (lane == 0) { als[wid] = ss; ald[wid] = sd; }
}
__global__ void k_initmax1(unsigned* __restrict__ menc, const float* __restrict__ als,
                           const float* __restrict__ ald, int n) {
  int i = blockIdx.x * blockDim.x + threadIdx.x;
  if (i >= n) return;
  menc[i] = fenc(lrelu(als[i] + ald[i]));
}
__global__ void k_edge_max1(unsigned* __restrict__ menc, const float* __restrict__ als,
                            const float* __restrict__ ald, const int* __restrict__ src,
                            const int* __restrict__ dst, int e) {
  int i = blockIdx.x * blockDim.x + threadIdx.x;
  if (i >= e) return;
  int s = src[i], d = dst[i];
  atomicMax(&menc[d], fenc(lrelu(als[s] + ald[d])));
}
__global__ void k_wsden1(float* __restrict__ mbuf, float* __restrict__ wsb,
                         float* __restrict__ den, const float* __restrict__ als,
                         const float* __restrict__ ald, int n) {
  int i = blockIdx.x * blockDim.x + threadIdx.x;
  if (i >= n) return;
  float mv = fdec(((const unsigned*)mbuf)[i]);
  mbuf[i] = mv;  // decode in place
  float w = expf(lrelu(als[i] + ald[i]) - mv);
  wsb[i] = w;
  den[i] = w;
}
__global__ void k_edge_we1(float* __restrict__ den, float* __restrict__ we,
                           const float* __restrict__ mbuf, const float* __restrict__ als,
                           const float* __restrict__ ald, const int* __restrict__ src,
                           const int* __restrict__ dst, int e) {
  int i = blockIdx.x * blockDim.x + threadIdx.x;
  if (i >= e) return;
  int s = src[i], d = dst[i];
  float w = expf(lrelu(als[s] + ald[d]) - mbuf[d]);
  we[i] = w;
  atomAddF(&den[d], w);
}
__global__ void k_init_out1(float* __restrict__ out, int ldO, int col0,
                            const float* __restrict__ h, int ldH,
                            const float* __restrict__ wsb, int n, int C) {
  long long idx = (long long)blockIdx.x * blockDim.x + threadIdx.x;
  if (idx >= (long long)n * C) return;
  int node = (int)(idx / C);
  int c = (int)(idx % C);
  out[(size_t)node * ldO + col0 + c] = wsb[node] * h[(size_t)node * ldH + c];
}
__global__ void k_edge_agg1(float* __restrict__ out, int ldO, int col0,
                            const float* __restrict__ h, int ldH,
                            const float* __restrict__ we, const int* __restrict__ src,
                            const int* __restrict__ dst, int e, int C) {
  long long idx = (long long)blockIdx.x * blockDim.x + threadIdx.x;
  if (idx >= (long long)e * C) return;
  int ed = (int)(idx / C);
  int c = (int)(idx % C);
  int s = src[ed], d = dst[ed];
  atomAddF(&out[(size_t)d * ldO + col0 + c], we[ed] * h[(size_t)s * ldH + c]);
}
__global__ void k_gat_epilogue(float* __restrict__ X, const float* __restrict__ den,
                               const float* __restrict__ bias, const float* __restrict__ g,
                               const float* __restrict__ b, const float* __restrict__ m,
                               const float* __restrict__ v, int n, int C) {
  long long idx = (long long)blockIdx.x * blockDim.x + threadIdx.x;
  int HC = 3 * C;
  if (idx >= (long long)n * HC) return;
  int node = (int)(idx / HC);
  int f = (int)(idx % HC);
  int hh = f / C;
  float val = X[idx] / den[(size_t)hh * n + node] + bias[f];
  val = fmaxf(val, 0.f);
  X[idx] = (val - m[f]) * rsqrtf(v[f] + BN_EPS) * g[f] + b[f];
}

// ---------------- pooling & final FC ----------------
__global__ void k_pool_add(float* __restrict__ pooled, const float* __restrict__ act,
                           const int* __restrict__ batch, int n, int F, int off) {
  long long idx = (long long)blockIdx.x * blockDim.x + threadIdx.x;
  if (idx >= (long long)n * F) return;
  int node = (int)(idx / F);
  int f = (int)(idx % F);
  atomAddF(&pooled[(size_t)batch[node] * 512 + off + f], act[idx]);
}
__global__ void k_fc3(const float* __restrict__ in, const float* __restrict__ w,
                      const float* __restrict__ b, float* __restrict__ out, int g) {
  int wid = (blockIdx.x * blockDim.x + threadIdx.x) >> 6;
  int lane = threadIdx.x & 63;
  if (wid >= g) return;
  float v = in[wid * 64 + lane] * w[lane];
#pragma unroll
  for (int off = 32; off > 0; off >>= 1) v += __shfl_down(v, off);
  if (lane == 0) out[wid] = fmaxf(v + b[0], 0.f);
}

// ---------------- host side ----------------
static void gemm(hipStream_t s, const float* A, const float* W, const float* bias,
                 float* C, int M, int K, int Nsub, int ldW, int ldC, int col0, int flags) {
  dim3 grid(cdiv(Nsub, 64), cdiv(M, 64));
  k_gemm<<<grid, 256, 0, s>>>(A, W, bias, C, M, K, Nsub, ldW, ldC, col0, flags);
}

struct GatBufs {
  float *als, *ald, *mbuf, *wsb, *den, *we;
};

// one head: h [n, C] at stride ldH; writes out[:, col0:col0+C] (stride ldO)
static void gat_head(hipStream_t s, const float* h, int ldH, int C,
                     const float* a_s, const float* a_d,
                     const int* src, const int* dst,
                     float* out, int ldO, int col0, float* den_h, GatBufs& g) {
  k_logits1<<<cdiv((long long)N_NODES * 64, 256), 256, 0, s>>>(h, ldH, a_s, a_d, g.als, g.ald, N_NODES, C);
  k_initmax1<<<cdiv(N_NODES, 256), 256, 0, s>>>((unsigned*)g.mbuf, g.als, g.ald, N_NODES);
  k_edge_max1<<<cdiv(N_EDGES, 256), 256, 0, s>>>((unsigned*)g.mbuf, g.als, g.ald, src, dst, N_EDGES);
  k_wsden1<<<cdiv(N_NODES, 256), 256, 0, s>>>(g.mbuf, g.wsb, den_h, g.als, g.ald, N_NODES);
  k_edge_we1<<<cdiv(N_EDGES, 256), 256, 0, s>>>(den_h, g.we, g.mbuf, g.als, g.ald, src, dst, N_EDGES);
  k_init_out1<<<cdiv((long long)N_NODES * C, 256), 256, 0, s>>>(out, ldO, col0, h, ldH, g.wsb, N_NODES, C);
  k_edge_agg1<<<cdiv((long long)N_EDGES * C, 256), 256, 0, s>>>(out, ldO, col0, h, ldH, g.we, src, dst, N_EDGES, C);
}

extern "C" void kernel_launch(void* const* d_in, const int* in_sizes, int n_in,
                              void* d_out, int out_size, void* d_ws, size_t ws_size,
                              hipStream_t stream) {
  const float* x = (const float*)d_in[0];
  const int* ei = (const int*)d_in[1];
  const int* batch = (const int*)d_in[2];
  const float* gw1 = (const float*)d_in[3];  const float* gb1 = (const float*)d_in[4];
  const float* gw2 = (const float*)d_in[5];  const float* gb2 = (const float*)d_in[6];
  const float* gw3 = (const float*)d_in[7];  const float* gb3 = (const float*)d_in[8];
  const float* g01g = (const float*)d_in[9];  const float* g01b = (const float*)d_in[10];
  const float* g01m = (const float*)d_in[11]; const float* g01v = (const float*)d_in[12];
  const float* g02g = (const float*)d_in[13]; const float* g02b = (const float*)d_in[14];
  const float* g02m = (const float*)d_in[15]; const float* g02v = (const float*)d_in[16];
  const float* g03g = (const float*)d_in[17]; const float* g03b = (const float*)d_in[18];
  const float* g03m = (const float*)d_in[19]; const float* g03v = (const float*)d_in[20];
  const float* g11g = (const float*)d_in[21]; const float* g11b = (const float*)d_in[22];
  const float* g11m = (const float*)d_in[23]; const float* g11v = (const float*)d_in[24];
  const float* g12g = (const float*)d_in[25]; const float* g12b = (const float*)d_in[26];
  const float* g12m = (const float*)d_in[27]; const float* g12v = (const float*)d_in[28];
  const float* g13g = (const float*)d_in[29]; const float* g13b = (const float*)d_in[30];
  const float* g13m = (const float*)d_in[31]; const float* g13v = (const float*)d_in[32];
  const float* aw1 = (const float*)d_in[33]; const float* as1 = (const float*)d_in[34];
  const float* ad1 = (const float*)d_in[35]; const float* ab1 = (const float*)d_in[36];
  const float* aw2 = (const float*)d_in[37]; const float* as2 = (const float*)d_in[38];
  const float* ad2 = (const float*)d_in[39]; const float* ab2 = (const float*)d_in[40];
  const float* aw3 = (const float*)d_in[41]; const float* as3 = (const float*)d_in[42];
  const float* ad3 = (const float*)d_in[43]; const float* ab3 = (const float*)d_in[44];
  const float* f1w = (const float*)d_in[45]; const float* f1b = (const float*)d_in[46];
  const float* f2w = (const float*)d_in[47]; const float* f2b = (const float*)d_in[48];
  const float* f3w = (const float*)d_in[49]; const float* f3b = (const float*)d_in[50];

  const int* src = ei;
  const int* dst = ei + N_EDGES;

  // ---- workspace carve (floats), peak ~240 MB ----
  size_t need = 0;
  need += (size_t)N_NODES * 768;   // OUT
  need += (size_t)N_NODES * 384;   // H
  need += (size_t)N_NODES;         // dinv
  need += (size_t)N_NODES * 4;     // als, ald, mbuf, wsb
  need += (size_t)N_NODES * 3;     // den (head-major)
  need += (size_t)N_EDGES;         // we
  need += (size_t)N_GRAPHS * (512 + 256 + 64);
  if (ws_size < need * sizeof(float)) return;  // diagnostic guard: clean fail, not a fault

  float* wp = (float*)d_ws;
  float* OUT = wp;    wp += (size_t)N_NODES * 768;
  float* H = wp;      wp += (size_t)N_NODES * 384;
  float* dinv = wp;   wp += N_NODES;
  GatBufs gb;
  gb.als = wp;  wp += N_NODES;
  gb.ald = wp;  wp += N_NODES;
  gb.mbuf = wp; wp += N_NODES;
  gb.wsb = wp;  wp += N_NODES;
  gb.den = wp;  wp += (size_t)N_NODES * 3;
  gb.we = wp;   wp += N_EDGES;
  float* pooled = wp; wp += (size_t)N_GRAPHS * 512;
  float* fc1 = wp;    wp += (size_t)N_GRAPHS * 256;
  float* fc2 = wp;    wp += (size_t)N_GRAPHS * 64;

  // degrees -> dinv (in place)
  k_fill1<<<cdiv(N_NODES, 256), 256, 0, stream>>>(dinv, N_NODES);
  k_deg_accum<<<cdiv(N_EDGES, 256), 256, 0, stream>>>(dinv, dst, N_EDGES);
  k_dinv<<<cdiv(N_NODES, 256), 256, 0, stream>>>(dinv, N_NODES);
  k_zero<<<cdiv((long long)N_GRAPHS * 512, 256), 256, 0, stream>>>(pooled, (long long)N_GRAPHS * 512);

  // ---- GCN path: X lives in OUT (compact ld=F) ----
  const float* gX = x; int gF = F_IN;
  struct { const float *w, *bias, *g, *b, *m, *v; int F; } gcn[3] = {
    {gw1, gb1, g01g, g01b, g01m, g01v, 256},
    {gw2, gb2, g02g, g02b, g02m, g02v, 128},
    {gw3, gb3, g03g, g03b, g03m, g03v, 128}};
  for (int l = 0; l < 3; l++) {
    int F = gcn[l].F;
    gemm(stream, gX, gcn[l].w, nullptr, H, N_NODES, gF, F, F, F, 0, 0);
    k_gcn_init<<<cdiv((long long)N_NODES * F, 256), 256, 0, stream>>>(OUT, H, dinv, gcn[l].bias, N_NODES, F);
    k_gcn_edge<<<cdiv((long long)N_EDGES * F, 256), 256, 0, stream>>>(OUT, H, dinv, src, dst, N_EDGES, F);
    k_relu_bn<<<cdiv((long long)N_NODES * F, 256), 256, 0, stream>>>(OUT, gcn[l].g, gcn[l].b, gcn[l].m, gcn[l].v, N_NODES, F);
    gX = OUT; gF = F;
  }
  k_pool_add<<<cdiv((long long)N_NODES * 128, 256), 256, 0, stream>>>(pooled, OUT, batch, N_NODES, 128, 0);

  // ---- GAT1: input x (external), C=256, per-head chunked GEMM into H ----
  {
    int C = 256, HC = 768;
    for (int hh = 0; hh < 3; hh++) {
      gemm(stream, x, aw1, nullptr, H, N_NODES, F_IN, C, HC, C, hh * C, 0);
      gat_head(stream, H, C, C, as1 + hh * C, ad1 + hh * C, src, dst,
               OUT, HC, hh * C, gb.den + (size_t)hh * N_NODES, gb);
    }
    k_gat_epilogue<<<cdiv((long long)N_NODES * HC, 256), 256, 0, stream>>>(
        OUT, gb.den, ab1, g11g, g11b, g11m, g11v, N_NODES, C);
  }

  // ---- GAT2 & GAT3: input OUT, full GEMM into H first, then per-head ----
  struct { const float *w, *s, *d, *bias, *g, *b, *m, *v; int K; } gat[2] = {
    {aw2, as2, ad2, ab2, g12g, g12b, g12m, g12v, 768},
    {aw3, as3, ad3, ab3, g13g, g13b, g13m, g13v, 384}};
  for (int l = 0; l < 2; l++) {
    int C = 128, HC = 384;
    gemm(stream, OUT, gat[l].w, nullptr, H, N_NODES, gat[l].K, HC, HC, HC, 0, 0);
    for (int hh = 0; hh < 3; hh++) {
      gat_head(stream, H + hh * C, HC, C, gat[l].s + hh * C, gat[l].d + hh * C,
               src, dst, OUT, HC, hh * C, gb.den + (size_t)hh * N_NODES, gb);
    }
    k_gat_epilogue<<<cdiv((long long)N_NODES * HC, 256), 256, 0, stream>>>(
        OUT, gb.den, gat[l].bias, gat[l].g, gat[l].b, gat[l].m, gat[l].v, N_NODES, C);
  }
  k_pool_add<<<cdiv((long long)N_NODES * 384, 256), 256, 0, stream>>>(pooled, OUT, batch, N_NODES, 384, 128);

  // ---- FC head ----
  gemm(stream, pooled, f1w, f1b, fc1, N_GRAPHS, 512, 256, 256, 256, 0, 3);
  gemm(stream, fc1, f2w, f2b, fc2, N_GRAPHS, 256, 64, 64, 64, 0, 3);
  k_fc3<<<cdiv((long long)N_GRAPHS * 64, 256), 256, 0, stream>>>(fc2, f3w, f3b, (float*)d_out, N_GRAPHS);
}

// Round 4
// 3473.789 us; speedup vs baseline: 1.3821x; 1.3821x over previous
//
#include <hip/hip_runtime.h>
#include <cstdint>
#include <cstddef>

#define N_NODES 50000
#define N_EDGES 200000
#define N_GRAPHS 2000
#define F_IN 373
#define NEG_SLOPE 0.2f
#define BN_EPS 1e-5f

typedef float f32x4 __attribute__((ext_vector_type(4)));
typedef short s16x8 __attribute__((ext_vector_type(8)));
typedef short s16x4 __attribute__((ext_vector_type(4)));
typedef unsigned int u32x4 __attribute__((ext_vector_type(4)));

static inline int cdiv(long long a, long long b) { return (int)((a + b - 1) / b); }

__device__ __forceinline__ float lrelu(float x) { return x > 0.f ? x : NEG_SLOPE * x; }

__device__ __forceinline__ void atomAddF(float* p, float v) {
#if defined(__HIP_DEVICE_COMPILE__)
  unsafeAtomicAdd(p, v);
#else
  atomicAdd(p, v);
#endif
}

__device__ __forceinline__ unsigned fenc(float x) {
  unsigned u = __float_as_uint(x);
  return (u & 0x80000000u) ? ~u : (u | 0x80000000u);
}
__device__ __forceinline__ float fdec(unsigned u) {
  unsigned b = (u & 0x80000000u) ? (u & 0x7fffffffu) : ~u;
  return __uint_as_float(b);
}

// RNE bf16 + hi/lo split: hi = bf16(f), lo = bf16(f - hi)
__device__ __forceinline__ unsigned short bf16rne(float f) {
  unsigned u = __float_as_uint(f);
  unsigned r = u + 0x7fffu + ((u >> 16) & 1u);
  return (unsigned short)(r >> 16);
}
__device__ __forceinline__ void split2(float f, unsigned short& hi, unsigned short& lo) {
  hi = bf16rne(f);
  float fh = __uint_as_float(((unsigned)hi) << 16);
  lo = bf16rne(f - fh);
}
__device__ __forceinline__ unsigned packsplit(float f) {
  unsigned short hi, lo;
  split2(f, hi, lo);
  return (((unsigned)hi) << 16) | (unsigned)lo;
}

// ---------------- utility ----------------
__global__ void k_zero(float* p, long long n) {
  long long i = (long long)blockIdx.x * blockDim.x + threadIdx.x;
  if (i < n) p[i] = 0.f;
}
__global__ void k_fill1(float* p, int n) {
  int i = blockIdx.x * blockDim.x + threadIdx.x;
  if (i < n) p[i] = 1.0f;
}
__global__ void k_deg_accum(float* deg, const int* __restrict__ dst, int e) {
  int i = blockIdx.x * blockDim.x + threadIdx.x;
  if (i < e) atomAddF(&deg[dst[i]], 1.0f);
}
__global__ void k_dinv(float* deg, int n) {
  int i = blockIdx.x * blockDim.x + threadIdx.x;
  if (i < n) deg[i] = rsqrtf(deg[i]);
}

// build Wt[n, k] packed-split from W[k, col0+n], k < K (zero pad to Kpad)
__global__ void k_buildwt(const float* __restrict__ W, int ldW, int col0, int Nsub,
                          int K, int Kpad, unsigned* __restrict__ Wt) {
  int n = blockIdx.x * blockDim.x + threadIdx.x;
  int k = blockIdx.y;
  if (n >= Nsub) return;
  float v = (k < K) ? W[(size_t)k * ldW + col0 + n] : 0.f;
  Wt[(size_t)n * Kpad + k] = packsplit(v);
}

// ---------------- MFMA split-bf16 GEMM ----------------
// C[M, Nsub] (ld=ldC, col offset col0) = A[M, K] @ Wt^T   (Wt: [Nsub, Kpad])
// amode: 0 = fp32 scalar loads, k<Kact guard (unaligned / K-tail, e.g. x lda=373)
//        2 = fp32 float4 loads (lda%4==0, Kact==Kpad)
// Nsub must be a multiple of 128 (= gridDim.x*128).
__global__ __launch_bounds__(256) void k_mfma_gemm(
    const float* __restrict__ Ap, int lda, int amode, int Kact,
    const unsigned* __restrict__ Wt, int Kpad,
    float* __restrict__ C, int M, int ldC, int col0) {
  // LDS in MFMA-fragment-swizzled order:
  // elem(row,k) -> (row>>4)*512 + (k>>3)*128 + (row&15)*8 + (k&7)
  __shared__ unsigned short Ah[128 * 32], Al[128 * 32], Bh[128 * 32], Bl[128 * 32];
  const int bm = blockIdx.y * 128;
  const int bn = blockIdx.x * 128;
  const int tid = threadIdx.x;
  const int lane = tid & 63;
  const int wave = tid >> 6;
  const int wm = wave >> 1, wn = wave & 1;

  f32x4 acc[4][4];
#pragma unroll
  for (int i = 0; i < 4; i++)
#pragma unroll
    for (int j = 0; j < 4; j++) acc[i][j] = (f32x4){0.f, 0.f, 0.f, 0.f};

  const int ar = tid >> 1;          // tile row / Wt row (0..127)
  const int ak0 = (tid & 1) * 16;   // k sub-offset (two threads cover 32 k's)
  const bool arok = (bm + ar) < M;

  for (int k0 = 0; k0 < Kpad; k0 += 32) {
    // ---- stage A (hi/lo split) ----
#pragma unroll
    for (int i = 0; i < 4; i++) {
      int k = ak0 + 4 * i;
      unsigned short hv[4], lv[4];
      if (amode == 2) {
        const float* ap = Ap + (size_t)(bm + ar) * lda + k0 + k;
        f32x4 v = arok ? *(const f32x4*)ap : (f32x4){0.f, 0.f, 0.f, 0.f};
#pragma unroll
        for (int u = 0; u < 4; u++) split2(v[u], hv[u], lv[u]);
      } else {
        const float* ap = Ap + (size_t)(bm + ar) * lda;
#pragma unroll
        for (int u = 0; u < 4; u++) {
          int kc = k0 + k + u;
          float f = (arok && kc < Kact) ? ap[kc] : 0.f;
          split2(f, hv[u], lv[u]);
        }
      }
      int eb = ((ar >> 4) << 9) + ((k >> 3) << 7) + ((ar & 15) << 3) + (k & 7);
      *(s16x4*)&Ah[eb] = *(s16x4*)hv;
      *(s16x4*)&Al[eb] = *(s16x4*)lv;
    }
    // ---- stage B (hi/lo) from packed Wt ----
#pragma unroll
    for (int i = 0; i < 4; i++) {
      int k = ak0 + 4 * i;
      const unsigned* bp = Wt + (size_t)(bn + ar) * Kpad + k0 + k;
      u32x4 v = *(const u32x4*)bp;
      unsigned short hv[4], lv[4];
#pragma unroll
      for (int u = 0; u < 4; u++) { hv[u] = (unsigned short)(v[u] >> 16); lv[u] = (unsigned short)(v[u] & 0xffffu); }
      int eb = ((ar >> 4) << 9) + ((k >> 3) << 7) + ((ar & 15) << 3) + (k & 7);
      *(s16x4*)&Bh[eb] = *(s16x4*)hv;
      *(s16x4*)&Bl[eb] = *(s16x4*)lv;
    }
    __syncthreads();
    // ---- compute: 48 MFMAs / wave / K-tile ----
    const int fbase = ((lane >> 4) << 7) + ((lane & 15) << 3);
    const int abase = (wm << 11) + fbase;
    const int bbase = (wn << 11) + fbase;
    s16x8 ah[4], al[4];
#pragma unroll
    for (int g = 0; g < 4; g++) {
      ah[g] = *(const s16x8*)&Ah[abase + (g << 9)];
      al[g] = *(const s16x8*)&Al[abase + (g << 9)];
    }
#pragma unroll
    for (int j = 0; j < 4; j++) {
      s16x8 bhj = *(const s16x8*)&Bh[bbase + (j << 9)];
      s16x8 blj = *(const s16x8*)&Bl[bbase + (j << 9)];
#pragma unroll
      for (int i = 0; i < 4; i++) {
        acc[i][j] = __builtin_amdgcn_mfma_f32_16x16x32_bf16(ah[i], bhj, acc[i][j], 0, 0, 0);
        acc[i][j] = __builtin_amdgcn_mfma_f32_16x16x32_bf16(al[i], bhj, acc[i][j], 0, 0, 0);
        acc[i][j] = __builtin_amdgcn_mfma_f32_16x16x32_bf16(ah[i], blj, acc[i][j], 0, 0, 0);
      }
    }
    __syncthreads();
  }
  // ---- write C: col=lane&15, row=(lane>>4)*4+reg  [m89-verified] ----
  const int crow = bm + wm * 64;
  const int ccol = bn + wn * 64;
#pragma unroll
  for (int i = 0; i < 4; i++) {
#pragma unroll
    for (int j = 0; j < 4; j++) {
      int r0 = crow + i * 16 + ((lane >> 4) << 2);
      int cc = ccol + j * 16 + (lane & 15);
#pragma unroll
      for (int r = 0; r < 4; r++) {
        if (r0 + r < M) C[(size_t)(r0 + r) * ldC + col0 + cc] = acc[i][j][r];
      }
    }
  }
}

// -------- small fp32 GEMM (FC head only) --------
__global__ __launch_bounds__(256) void k_gemm(
    const float* __restrict__ A, const float* __restrict__ W,
    const float* __restrict__ bias, float* __restrict__ C,
    int M, int K, int Nsub, int ldW, int ldC, int col0, int flags) {
  __shared__ float As[16][68];
  __shared__ float Bs[16][68];
  const int bm = blockIdx.y * 64;
  const int bn = blockIdx.x * 64;
  const int tid = threadIdx.x;
  const int tm = (tid >> 4) << 2;
  const int tn = (tid & 15) << 2;
  float acc[4][4] = {};
  for (int k0 = 0; k0 < K; k0 += 16) {
    {
      int idx = tid * 4;
      int row = idx >> 4;
      int kk = idx & 15;
      const float* ap = A + (size_t)(bm + row) * K + k0 + kk;
      bool rok = (bm + row) < M;
#pragma unroll
      for (int i = 0; i < 4; i++) {
        int kcur = k0 + kk + i;
        As[kk + i][row] = (rok && kcur < K) ? ap[i] : 0.f;
      }
    }
#pragma unroll
    for (int i = 0; i < 4; i++) {
      int idx = tid + i * 256;
      int kk = idx >> 6;
      int nn = idx & 63;
      int kcur = k0 + kk;
      Bs[kk][nn] = (kcur < K && (bn + nn) < Nsub)
                       ? W[(size_t)kcur * ldW + col0 + bn + nn] : 0.f;
    }
    __syncthreads();
#pragma unroll
    for (int kk = 0; kk < 16; kk++) {
      float av[4], bv[4];
#pragma unroll
      for (int i = 0; i < 4; i++) av[i] = As[kk][tm + i];
#pragma unroll
      for (int j = 0; j < 4; j++) bv[j] = Bs[kk][tn + j];
#pragma unroll
      for (int i = 0; i < 4; i++)
#pragma unroll
        for (int j = 0; j < 4; j++) acc[i][j] += av[i] * bv[j];
    }
    __syncthreads();
  }
#pragma unroll
  for (int i = 0; i < 4; i++) {
    int row = bm + tm + i;
    if (row >= M) continue;
#pragma unroll
    for (int j = 0; j < 4; j++) {
      int col = bn + tn + j;
      if (col >= Nsub) continue;
      float v = acc[i][j];
      if (flags & 1) v += bias[col0 + col];
      if (flags & 2) v = fmaxf(v, 0.f);
      C[(size_t)row * ldC + col] = v;
    }
  }
}

// ---------------- GCN ----------------
__global__ void k_gcn_init(float* __restrict__ out, const float* __restrict__ h,
                           const float* __restrict__ dinv, const float* __restrict__ bias,
                           int n, int F) {
  long long idx = (long long)blockIdx.x * blockDim.x + threadIdx.x;
  if (idx >= (long long)n * F) return;
  int node = (int)(idx / F);
  int f = (int)(idx % F);
  float di = dinv[node];
  out[idx] = di * di * h[idx] + bias[f];
}
__global__ void k_gcn_edge(float* __restrict__ out, const float* __restrict__ h,
                           const float* __restrict__ dinv, const int* __restrict__ src,
                           const int* __restrict__ dst, int e, int F) {
  long long idx = (long long)blockIdx.x * blockDim.x + threadIdx.x;
  if (idx >= (long long)e * F) return;
  int ed = (int)(idx / F);
  int f = (int)(idx % F);
  int s = src[ed], d = dst[ed];
  atomAddF(&out[(size_t)d * F + f], dinv[s] * dinv[d] * h[(size_t)s * F + f]);
}
__global__ void k_relu_bn(float* __restrict__ X, const float* __restrict__ g,
                          const float* __restrict__ b, const float* __restrict__ m,
                          const float* __restrict__ v, int n, int F) {
  long long idx = (long long)blockIdx.x * blockDim.x + threadIdx.x;
  if (idx >= (long long)n * F) return;
  int f = (int)(idx % F);
  float val = fmaxf(X[idx], 0.f);
  X[idx] = (val - m[f]) * rsqrtf(v[f] + BN_EPS) * g[f] + b[f];
}

// ---------------- GAT (single-head kernels) ----------------
__global__ void k_logits1(const float* __restrict__ h, int ldH,
                          const float* __restrict__ a_s, const float* __restrict__ a_d,
                          float* __restrict__ als, float* __restrict__ ald, int n, int C) {
  int wid = (blockIdx.x * blockDim.x + threadIdx.x) >> 6;
  int lane = threadIdx.x & 63;
  if (wid >= n) return;
  const float* hp = h + (size_t)wid * ldH;
  float ss = 0.f, sd = 0.f;
  for (int c = lane; c < C; c += 64) {
    float hv = hp[c];
    ss += hv * a_s[c];
    sd += hv * a_d[c];
  }
#pragma unroll
  for (int off = 32; off > 0; off >>= 1) {
    ss += __shfl_down(ss, off);
    sd += __shfl_down(sd, off);
  }
  if (lane == 0) { als[wid] = ss; ald[wid] = sd; }
}
__global__ void k_initmax1(unsigned* __restrict__ menc, const float* __restrict__ als,
                           const float* __restrict__ ald, int n) {
  int i = blockIdx.x * blockDim.x + threadIdx.x;
  if (i >= n) return;
  menc[i] = fenc(lrelu(als[i] + ald[i]));
}
__global__ void k_edge_max1(unsigned* __restrict__ menc, const float* __restrict__ als,
                            const float* __restrict__ ald, const int* __restrict__ src,
                            const int* __restrict__ dst, int e) {
  int i = blockIdx.x * blockDim.x + threadIdx.x;
  if (i >= e) return;
  int s = src[i], d = dst[i];
  atomicMax(&menc[d], fenc(lrelu(als[s] + ald[d])));
}
__global__ void k_wsden1(float* __restrict__ mbuf, float* __restrict__ wsb,
                         float* __restrict__ den, const float* __restrict__ als,
                         const float* __restrict__ ald, int n) {
  int i = blockIdx.x * blockDim.x + threadIdx.x;
  if (i >= n) return;
  float mv = fdec(((const unsigned*)mbuf)[i]);
  mbuf[i] = mv;
  float w = expf(lrelu(als[i] + ald[i]) - mv);
  wsb[i] = w;
  den[i] = w;
}
__global__ void k_edge_we1(float* __restrict__ den, float* __restrict__ we,
                           const float* __restrict__ mbuf, const float* __restrict__ als,
                           const float* __restrict__ ald, const int* __restrict__ src,
                           const int* __restrict__ dst, int e) {
  int i = blockIdx.x * blockDim.x + threadIdx.x;
  if (i >= e) return;
  int s = src[i], d = dst[i];
  float w = expf(lrelu(als[s] + ald[d]) - mbuf[d]);
  we[i] = w;
  atomAddF(&den[d], w);
}
__global__ void k_init_out1(float* __restrict__ out, int ldO, int col0,
                            const float* __restrict__ h, int ldH,
                            const float* __restrict__ wsb, int n, int C) {
  long long idx = (long long)blockIdx.x * blockDim.x + threadIdx.x;
  if (idx >= (long long)n * C) return;
  int node = (int)(idx / C);
  int c = (int)(idx % C);
  out[(size_t)node * ldO + col0 + c] = wsb[node] * h[(size_t)node * ldH + c];
}
__global__ void k_edge_agg1(float* __restrict__ out, int ldO, int col0,
                            const float* __restrict__ h, int ldH,
                            const float* __restrict__ we, const int* __restrict__ src,
                            const int* __restrict__ dst, int e, int C) {
  long long idx = (long long)blockIdx.x * blockDim.x + threadIdx.x;
  if (idx >= (long long)e * C) return;
  int ed = (int)(idx / C);
  int c = (int)(idx % C);
  int s = src[ed], d = dst[ed];
  atomAddF(&out[(size_t)d * ldO + col0 + c], we[ed] * h[(size_t)s * ldH + c]);
}
__global__ void k_gat_epilogue(float* __restrict__ X, const float* __restrict__ den,
                               const float* __restrict__ bias, const float* __restrict__ g,
                               const float* __restrict__ b, const float* __restrict__ m,
                               const float* __restrict__ v, int n, int C) {
  long long idx = (long long)blockIdx.x * blockDim.x + threadIdx.x;
  int HC = 3 * C;
  if (idx >= (long long)n * HC) return;
  int node = (int)(idx / HC);
  int f = (int)(idx % HC);
  int hh = f / C;
  float val = X[idx] / den[(size_t)hh * n + node] + bias[f];
  val = fmaxf(val, 0.f);
  X[idx] = (val - m[f]) * rsqrtf(v[f] + BN_EPS) * g[f] + b[f];
}

// ---------------- pooling & final FC ----------------
__global__ void k_pool_add(float* __restrict__ pooled, const float* __restrict__ act,
                           const int* __restrict__ batch, int n, int F, int off) {
  long long idx = (long long)blockIdx.x * blockDim.x + threadIdx.x;
  if (idx >= (long long)n * F) return;
  int node = (int)(idx / F);
  int f = (int)(idx % F);
  atomAddF(&pooled[(size_t)batch[node] * 512 + off + f], act[idx]);
}
__global__ void k_fc3(const float* __restrict__ in, const float* __restrict__ w,
                      const float* __restrict__ b, float* __restrict__ out, int g) {
  int wid = (blockIdx.x * blockDim.x + threadIdx.x) >> 6;
  int lane = threadIdx.x & 63;
  if (wid >= g) return;
  float v = in[wid * 64 + lane] * w[lane];
#pragma unroll
  for (int off = 32; off > 0; off >>= 1) v += __shfl_down(v, off);
  if (lane == 0) out[wid] = fmaxf(v + b[0], 0.f);
}

// ---------------- host side ----------------
static void gemm_fp32(hipStream_t s, const float* A, const float* W, const float* bias,
                      float* C, int M, int K, int Nsub, int ldW, int ldC, int col0, int flags) {
  dim3 grid(cdiv(Nsub, 64), cdiv(M, 64));
  k_gemm<<<grid, 256, 0, s>>>(A, W, bias, C, M, K, Nsub, ldW, ldC, col0, flags);
}

// split-bf16 MFMA GEMM incl. Wt build
static void gemm_mfma(hipStream_t s, const float* A, int lda, int amode,
                      const float* W, int ldW, int wcol0, int K, int Kpad,
                      unsigned* Wt, float* C, int M, int Nsub, int ldC, int ccol0) {
  dim3 wg(cdiv(Nsub, 256), Kpad);
  k_buildwt<<<wg, 256, 0, s>>>(W, ldW, wcol0, Nsub, K, Kpad, Wt);
  dim3 grid(Nsub / 128, cdiv(M, 128));
  k_mfma_gemm<<<grid, 256, 0, s>>>(A, lda, amode, K, Wt, Kpad, C, M, ldC, ccol0);
}

struct GatBufs {
  float *als, *ald, *mbuf, *wsb, *den, *we;
};

static void gat_head(hipStream_t s, const float* h, int ldH, int C,
                     const float* a_s, const float* a_d,
                     const int* src, const int* dst,
                     float* out, int ldO, int col0, float* den_h, GatBufs& g) {
  k_logits1<<<cdiv((long long)N_NODES * 64, 256), 256, 0, s>>>(h, ldH, a_s, a_d, g.als, g.ald, N_NODES, C);
  k_initmax1<<<cdiv(N_NODES, 256), 256, 0, s>>>((unsigned*)g.mbuf, g.als, g.ald, N_NODES);
  k_edge_max1<<<cdiv(N_EDGES, 256), 256, 0, s>>>((unsigned*)g.mbuf, g.als, g.ald, src, dst, N_EDGES);
  k_wsden1<<<cdiv(N_NODES, 256), 256, 0, s>>>(g.mbuf, g.wsb, den_h, g.als, g.ald, N_NODES);
  k_edge_we1<<<cdiv(N_EDGES, 256), 256, 0, s>>>(den_h, g.we, g.mbuf, g.als, g.ald, src, dst, N_EDGES);
  k_init_out1<<<cdiv((long long)N_NODES * C, 256), 256, 0, s>>>(out, ldO, col0, h, ldH, g.wsb, N_NODES, C);
  k_edge_agg1<<<cdiv((long long)N_EDGES * C, 256), 256, 0, s>>>(out, ldO, col0, h, ldH, g.we, src, dst, N_EDGES, C);
}

extern "C" void kernel_launch(void* const* d_in, const int* in_sizes, int n_in,
                              void* d_out, int out_size, void* d_ws, size_t ws_size,
                              hipStream_t stream) {
  const float* x = (const float*)d_in[0];
  const int* ei = (const int*)d_in[1];
  const int* batch = (const int*)d_in[2];
  const float* gw1 = (const float*)d_in[3];  const float* gb1 = (const float*)d_in[4];
  const float* gw2 = (const float*)d_in[5];  const float* gb2 = (const float*)d_in[6];
  const float* gw3 = (const float*)d_in[7];  const float* gb3 = (const float*)d_in[8];
  const float* g01g = (const float*)d_in[9];  const float* g01b = (const float*)d_in[10];
  const float* g01m = (const float*)d_in[11]; const float* g01v = (const float*)d_in[12];
  const float* g02g = (const float*)d_in[13]; const float* g02b = (const float*)d_in[14];
  const float* g02m = (const float*)d_in[15]; const float* g02v = (const float*)d_in[16];
  const float* g03g = (const float*)d_in[17]; const float* g03b = (const float*)d_in[18];
  const float* g03m = (const float*)d_in[19]; const float* g03v = (const float*)d_in[20];
  const float* g11g = (const float*)d_in[21]; const float* g11b = (const float*)d_in[22];
  const float* g11m = (const float*)d_in[23]; const float* g11v = (const float*)d_in[24];
  const float* g12g = (const float*)d_in[25]; const float* g12b = (const float*)d_in[26];
  const float* g12m = (const float*)d_in[27]; const float* g12v = (const float*)d_in[28];
  const float* g13g = (const float*)d_in[29]; const float* g13b = (const float*)d_in[30];
  const float* g13m = (const float*)d_in[31]; const float* g13v = (const float*)d_in[32];
  const float* aw1 = (const float*)d_in[33]; const float* as1 = (const float*)d_in[34];
  const float* ad1 = (const float*)d_in[35]; const float* ab1 = (const float*)d_in[36];
  const float* aw2 = (const float*)d_in[37]; const float* as2 = (const float*)d_in[38];
  const float* ad2 = (const float*)d_in[39]; const float* ab2 = (const float*)d_in[40];
  const float* aw3 = (const float*)d_in[41]; const float* as3 = (const float*)d_in[42];
  const float* ad3 = (const float*)d_in[43]; const float* ab3 = (const float*)d_in[44];
  const float* f1w = (const float*)d_in[45]; const float* f1b = (const float*)d_in[46];
  const float* f2w = (const float*)d_in[47]; const float* f2b = (const float*)d_in[48];
  const float* f3w = (const float*)d_in[49]; const float* f3b = (const float*)d_in[50];

  const int* src = ei;
  const int* dst = ei + N_EDGES;

  // ---- workspace carve: EXACTLY round-2's passing footprint (239.456 MB) ----
  size_t need = 0;
  need += (size_t)N_NODES * 768;   // OUT
  need += (size_t)N_NODES * 384;   // H
  need += (size_t)N_NODES;         // dinv
  need += (size_t)N_NODES * 4;     // als, ald, mbuf, wsb
  need += (size_t)N_NODES * 3;     // den
  need += (size_t)N_EDGES;         // we
  need += (size_t)N_GRAPHS * (512 + 256 + 64);  // pooled + fc1/fc2 (fc region aliased by Wt)
  if (ws_size < need * sizeof(float)) return;  // clean-fail guard

  float* wp = (float*)d_ws;
  float* OUT = wp;     wp += (size_t)N_NODES * 768;
  float* H = wp;       wp += (size_t)N_NODES * 384;
  float* dinv = wp;    wp += N_NODES;
  GatBufs gb;
  gb.als = wp;  wp += N_NODES;
  gb.ald = wp;  wp += N_NODES;
  gb.mbuf = wp; wp += N_NODES;
  gb.wsb = wp;  wp += N_NODES;
  gb.den = wp;  wp += (size_t)N_NODES * 3;
  gb.we = wp;   wp += N_EDGES;
  float* pooled = wp; wp += (size_t)N_GRAPHS * 512;
  float* fc1 = wp;    wp += (size_t)N_GRAPHS * 256;
  float* fc2 = wp;    wp += (size_t)N_GRAPHS * 64;
  // Wt (max 384*768 u32 = 294912 words) aliases fc1+fc2 (640000 words).
  // Last Wt use (GAT3 mfma GEMM) precedes first fc1 write in stream order.
  unsigned* Wt = (unsigned*)fc1;

  // degrees -> dinv; zero pooled
  k_fill1<<<cdiv(N_NODES, 256), 256, 0, stream>>>(dinv, N_NODES);
  k_deg_accum<<<cdiv(N_EDGES, 256), 256, 0, stream>>>(dinv, dst, N_EDGES);
  k_dinv<<<cdiv(N_NODES, 256), 256, 0, stream>>>(dinv, N_NODES);
  k_zero<<<cdiv((long long)N_GRAPHS * 512, 256), 256, 0, stream>>>(pooled, (long long)N_GRAPHS * 512);

  // ---- GCN path ----
  struct { const float *w, *bias, *g, *b, *m, *v; int F; } gcn[3] = {
    {gw1, gb1, g01g, g01b, g01m, g01v, 256},
    {gw2, gb2, g02g, g02b, g02m, g02v, 128},
    {gw3, gb3, g03g, g03b, g03m, g03v, 128}};
  int gF = F_IN;
  for (int l = 0; l < 3; l++) {
    int F = gcn[l].F;
    if (l == 0)
      gemm_mfma(stream, x, F_IN, 0, gcn[l].w, F, 0, F_IN, 384, Wt, H, N_NODES, F, F, 0);
    else
      gemm_mfma(stream, OUT, gF, 2, gcn[l].w, F, 0, gF, gF, Wt, H, N_NODES, F, F, 0);
    k_gcn_init<<<cdiv((long long)N_NODES * F, 256), 256, 0, stream>>>(OUT, H, dinv, gcn[l].bias, N_NODES, F);
    k_gcn_edge<<<cdiv((long long)N_EDGES * F, 256), 256, 0, stream>>>(OUT, H, dinv, src, dst, N_EDGES, F);
    k_relu_bn<<<cdiv((long long)N_NODES * F, 256), 256, 0, stream>>>(OUT, gcn[l].g, gcn[l].b, gcn[l].m, gcn[l].v, N_NODES, F);
    gF = F;
  }
  k_pool_add<<<cdiv((long long)N_NODES * 128, 256), 256, 0, stream>>>(pooled, OUT, batch, N_NODES, 128, 0);

  // ---- GAT1: input x (fp32 scalar staging), C=256, per-head ----
  {
    int C = 256, HC = 768;
    for (int hh = 0; hh < 3; hh++) {
      gemm_mfma(stream, x, F_IN, 0, aw1, HC, hh * C, F_IN, 384, Wt, H, N_NODES, C, C, 0);
      gat_head(stream, H, C, C, as1 + hh * C, ad1 + hh * C, src, dst,
               OUT, HC, hh * C, gb.den + (size_t)hh * N_NODES, gb);
    }
    k_gat_epilogue<<<cdiv((long long)N_NODES * HC, 256), 256, 0, stream>>>(
        OUT, gb.den, ab1, g11g, g11b, g11m, g11v, N_NODES, C);
  }

  // ---- GAT2 & GAT3 ----
  struct { const float *w, *s, *d, *bias, *g, *b, *m, *v; int K; } gat[2] = {
    {aw2, as2, ad2, ab2, g12g, g12b, g12m, g12v, 768},
    {aw3, as3, ad3, ab3, g13g, g13b, g13m, g13v, 384}};
  for (int l = 0; l < 2; l++) {
    int C = 128, HC = 384;
    gemm_mfma(stream, OUT, gat[l].K, 2, gat[l].w, HC, 0, gat[l].K, gat[l].K, Wt, H, N_NODES, HC, HC, 0);
    for (int hh = 0; hh < 3; hh++) {
      gat_head(stream, H + hh * C, HC, C, gat[l].s + hh * C, gat[l].d + hh * C,
               src, dst, OUT, HC, hh * C, gb.den + (size_t)hh * N_NODES, gb);
    }
    k_gat_epilogue<<<cdiv((long long)N_NODES * HC, 256), 256, 0, stream>>>(
        OUT, gb.den, gat[l].bias, gat[l].g, gat[l].b, gat[l].m, gat[l].v, N_NODES, C);
  }
  k_pool_add<<<cdiv((long long)N_NODES * 384, 256), 256, 0, stream>>>(pooled, OUT, batch, N_NODES, 384, 128);

  // ---- FC head (fp32, tiny) ----
  gemm_fp32(stream, pooled, f1w, f1b, fc1, N_GRAPHS, 512, 256, 256, 256, 0, 3);
  gemm_fp32(stream, fc1, f2w, f2b, fc2, N_GRAPHS, 256, 64, 64, 64, 0, 3);
  k_fc3<<<cdiv((long long)N_GRAPHS * 64, 256), 256, 0, stream>>>(fc2, f3w, f3b, (float*)d_out, N_GRAPHS);
}

// Round 5
// 2028.032 us; speedup vs baseline: 2.3673x; 1.7129x over previous
//
#include <hip/hip_runtime.h>
#include <cstdint>
#include <cstddef>

#define N_NODES 50000
#define N_EDGES 200000
#define N_GRAPHS 2000
#define F_IN 373
#define NEG_SLOPE 0.2f
#define BN_EPS 1e-5f

typedef float f32x4 __attribute__((ext_vector_type(4)));
typedef float f32x2 __attribute__((ext_vector_type(2)));
typedef short s16x8 __attribute__((ext_vector_type(8)));
typedef short s16x4 __attribute__((ext_vector_type(4)));
typedef unsigned int u32x4 __attribute__((ext_vector_type(4)));

template <int VPT> struct VecT;
template <> struct VecT<2> { using type = f32x2; };
template <> struct VecT<4> { using type = f32x4; };

static inline int cdiv(long long a, long long b) { return (int)((a + b - 1) / b); }

__device__ __forceinline__ float lrelu(float x) { return x > 0.f ? x : NEG_SLOPE * x; }

__device__ __forceinline__ void atomAddF(float* p, float v) {
#if defined(__HIP_DEVICE_COMPILE__)
  unsafeAtomicAdd(p, v);
#else
  atomicAdd(p, v);
#endif
}

// RNE bf16 + hi/lo split: hi = bf16(f), lo = bf16(f - hi)
__device__ __forceinline__ unsigned short bf16rne(float f) {
  unsigned u = __float_as_uint(f);
  unsigned r = u + 0x7fffu + ((u >> 16) & 1u);
  return (unsigned short)(r >> 16);
}
__device__ __forceinline__ void split2(float f, unsigned short& hi, unsigned short& lo) {
  hi = bf16rne(f);
  float fh = __uint_as_float(((unsigned)hi) << 16);
  lo = bf16rne(f - fh);
}
__device__ __forceinline__ unsigned packsplit(float f) {
  unsigned short hi, lo;
  split2(f, hi, lo);
  return (((unsigned)hi) << 16) | (unsigned)lo;
}

// ---------------- utility ----------------
__global__ void k_zero(float* p, long long n) {
  long long i = (long long)blockIdx.x * blockDim.x + threadIdx.x;
  if (i < n) p[i] = 0.f;
}
__global__ void k_zero_i(int* p, int n) {
  int i = blockIdx.x * blockDim.x + threadIdx.x;
  if (i < n) p[i] = 0;
}
__global__ void k_deg(int* __restrict__ deg, const int* __restrict__ dst, int e) {
  int i = blockIdx.x * blockDim.x + threadIdx.x;
  if (i < e) atomicAdd(&deg[dst[i]], 1);
}
__global__ void k_dinv(const int* __restrict__ deg, float* __restrict__ dinv, int n) {
  int i = blockIdx.x * blockDim.x + threadIdx.x;
  if (i < n) dinv[i] = rsqrtf((float)deg[i] + 1.0f);
}

// single-block exclusive scan of deg -> rowptr[0..n], zeroes cursor
__global__ void k_scan(const int* __restrict__ deg, int* __restrict__ rowptr,
                       int* __restrict__ cursor, int n) {
  __shared__ int wsum[16];
  __shared__ int carry_s;
  const int lane = threadIdx.x & 63;
  const int wid = threadIdx.x >> 6;
  if (threadIdx.x == 0) carry_s = 0;
  __syncthreads();
  for (int base = 0; base < n; base += 1024) {
    int i = base + threadIdx.x;
    int v = (i < n) ? deg[i] : 0;
    int s = v;
#pragma unroll
    for (int off = 1; off < 64; off <<= 1) {
      int t = __shfl_up(s, off);
      if (lane >= off) s += t;
    }
    if (lane == 63) wsum[wid] = s;
    __syncthreads();
    if (threadIdx.x == 0) {
      int acc = carry_s;
#pragma unroll
      for (int w = 0; w < 16; w++) { int t = wsum[w]; wsum[w] = acc; acc += t; }
      carry_s = acc;
    }
    __syncthreads();
    if (i < n) { rowptr[i] = wsum[wid] + s - v; cursor[i] = 0; }
    __syncthreads();
  }
  if (threadIdx.x == 0) rowptr[n] = carry_s;
}

__global__ void k_csr_scatter(const int* __restrict__ src, const int* __restrict__ dst,
                              const int* __restrict__ rowptr, int* __restrict__ cursor,
                              int* __restrict__ csr_src, int e) {
  int i = blockIdx.x * blockDim.x + threadIdx.x;
  if (i >= e) return;
  int d = dst[i];
  int pos = rowptr[d] + atomicAdd(&cursor[d], 1);
  csr_src[pos] = src[i];
}

// build Wt[n, k] packed-split from W[k, col0+n], k < K (zero pad to Kpad)
__global__ void k_buildwt(const float* __restrict__ W, int ldW, int col0, int Nsub,
                          int K, int Kpad, unsigned* __restrict__ Wt) {
  int n = blockIdx.x * blockDim.x + threadIdx.x;
  int k = blockIdx.y;
  if (n >= Nsub) return;
  float v = (k < K) ? W[(size_t)k * ldW + col0 + n] : 0.f;
  Wt[(size_t)n * Kpad + k] = packsplit(v);
}

// ---------------- MFMA split-bf16 GEMM (round-4 proven) ----------------
__global__ __launch_bounds__(256) void k_mfma_gemm(
    const float* __restrict__ Ap, int lda, int amode, int Kact,
    const unsigned* __restrict__ Wt, int Kpad,
    float* __restrict__ C, int M, int ldC, int col0) {
  __shared__ unsigned short Ah[128 * 32], Al[128 * 32], Bh[128 * 32], Bl[128 * 32];
  const int bm = blockIdx.y * 128;
  const int bn = blockIdx.x * 128;
  const int tid = threadIdx.x;
  const int lane = tid & 63;
  const int wave = tid >> 6;
  const int wm = wave >> 1, wn = wave & 1;

  f32x4 acc[4][4];
#pragma unroll
  for (int i = 0; i < 4; i++)
#pragma unroll
    for (int j = 0; j < 4; j++) acc[i][j] = (f32x4){0.f, 0.f, 0.f, 0.f};

  const int ar = tid >> 1;
  const int ak0 = (tid & 1) * 16;
  const bool arok = (bm + ar) < M;

  for (int k0 = 0; k0 < Kpad; k0 += 32) {
#pragma unroll
    for (int i = 0; i < 4; i++) {
      int k = ak0 + 4 * i;
      unsigned short hv[4], lv[4];
      if (amode == 2) {
        const float* ap = Ap + (size_t)(bm + ar) * lda + k0 + k;
        f32x4 v = arok ? *(const f32x4*)ap : (f32x4){0.f, 0.f, 0.f, 0.f};
#pragma unroll
        for (int u = 0; u < 4; u++) split2(v[u], hv[u], lv[u]);
      } else {
        const float* ap = Ap + (size_t)(bm + ar) * lda;
#pragma unroll
        for (int u = 0; u < 4; u++) {
          int kc = k0 + k + u;
          float f = (arok && kc < Kact) ? ap[kc] : 0.f;
          split2(f, hv[u], lv[u]);
        }
      }
      int eb = ((ar >> 4) << 9) + ((k >> 3) << 7) + ((ar & 15) << 3) + (k & 7);
      *(s16x4*)&Ah[eb] = *(s16x4*)hv;
      *(s16x4*)&Al[eb] = *(s16x4*)lv;
    }
#pragma unroll
    for (int i = 0; i < 4; i++) {
      int k = ak0 + 4 * i;
      const unsigned* bp = Wt + (size_t)(bn + ar) * Kpad + k0 + k;
      u32x4 v = *(const u32x4*)bp;
      unsigned short hv[4], lv[4];
#pragma unroll
      for (int u = 0; u < 4; u++) { hv[u] = (unsigned short)(v[u] >> 16); lv[u] = (unsigned short)(v[u] & 0xffffu); }
      int eb = ((ar >> 4) << 9) + ((k >> 3) << 7) + ((ar & 15) << 3) + (k & 7);
      *(s16x4*)&Bh[eb] = *(s16x4*)hv;
      *(s16x4*)&Bl[eb] = *(s16x4*)lv;
    }
    __syncthreads();
    const int fbase = ((lane >> 4) << 7) + ((lane & 15) << 3);
    const int abase = (wm << 11) + fbase;
    const int bbase = (wn << 11) + fbase;
    s16x8 ah[4], al[4];
#pragma unroll
    for (int g = 0; g < 4; g++) {
      ah[g] = *(const s16x8*)&Ah[abase + (g << 9)];
      al[g] = *(const s16x8*)&Al[abase + (g << 9)];
    }
#pragma unroll
    for (int j = 0; j < 4; j++) {
      s16x8 bhj = *(const s16x8*)&Bh[bbase + (j << 9)];
      s16x8 blj = *(const s16x8*)&Bl[bbase + (j << 9)];
#pragma unroll
      for (int i = 0; i < 4; i++) {
        acc[i][j] = __builtin_amdgcn_mfma_f32_16x16x32_bf16(ah[i], bhj, acc[i][j], 0, 0, 0);
        acc[i][j] = __builtin_amdgcn_mfma_f32_16x16x32_bf16(al[i], bhj, acc[i][j], 0, 0, 0);
        acc[i][j] = __builtin_amdgcn_mfma_f32_16x16x32_bf16(ah[i], blj, acc[i][j], 0, 0, 0);
      }
    }
    __syncthreads();
  }
  const int crow = bm + wm * 64;
  const int ccol = bn + wn * 64;
#pragma unroll
  for (int i = 0; i < 4; i++) {
#pragma unroll
    for (int j = 0; j < 4; j++) {
      int r0 = crow + i * 16 + ((lane >> 4) << 2);
      int cc = ccol + j * 16 + (lane & 15);
#pragma unroll
      for (int r = 0; r < 4; r++) {
        if (r0 + r < M) C[(size_t)(r0 + r) * ldC + col0 + cc] = acc[i][j][r];
      }
    }
  }
}

// -------- small fp32 GEMM (FC head only) --------
__global__ __launch_bounds__(256) void k_gemm(
    const float* __restrict__ A, const float* __restrict__ W,
    const float* __restrict__ bias, float* __restrict__ C,
    int M, int K, int Nsub, int ldW, int ldC, int col0, int flags) {
  __shared__ float As[16][68];
  __shared__ float Bs[16][68];
  const int bm = blockIdx.y * 64;
  const int bn = blockIdx.x * 64;
  const int tid = threadIdx.x;
  const int tm = (tid >> 4) << 2;
  const int tn = (tid & 15) << 2;
  float acc[4][4] = {};
  for (int k0 = 0; k0 < K; k0 += 16) {
    {
      int idx = tid * 4;
      int row = idx >> 4;
      int kk = idx & 15;
      const float* ap = A + (size_t)(bm + row) * K + k0 + kk;
      bool rok = (bm + row) < M;
#pragma unroll
      for (int i = 0; i < 4; i++) {
        int kcur = k0 + kk + i;
        As[kk + i][row] = (rok && kcur < K) ? ap[i] : 0.f;
      }
    }
#pragma unroll
    for (int i = 0; i < 4; i++) {
      int idx = tid + i * 256;
      int kk = idx >> 6;
      int nn = idx & 63;
      int kcur = k0 + kk;
      Bs[kk][nn] = (kcur < K && (bn + nn) < Nsub)
                       ? W[(size_t)kcur * ldW + col0 + bn + nn] : 0.f;
    }
    __syncthreads();
#pragma unroll
    for (int kk = 0; kk < 16; kk++) {
      float av[4], bv[4];
#pragma unroll
      for (int i = 0; i < 4; i++) av[i] = As[kk][tm + i];
#pragma unroll
      for (int j = 0; j < 4; j++) bv[j] = Bs[kk][tn + j];
#pragma unroll
      for (int i = 0; i < 4; i++)
#pragma unroll
        for (int j = 0; j < 4; j++) acc[i][j] += av[i] * bv[j];
    }
    __syncthreads();
  }
#pragma unroll
  for (int i = 0; i < 4; i++) {
    int row = bm + tm + i;
    if (row >= M) continue;
#pragma unroll
    for (int j = 0; j < 4; j++) {
      int col = bn + tn + j;
      if (col >= Nsub) continue;
      float v = acc[i][j];
      if (flags & 1) v += bias[col0 + col];
      if (flags & 2) v = fmaxf(v, 0.f);
      C[(size_t)row * ldC + col] = v;
    }
  }
}

// ---------------- fused GCN aggregation + ReLU + BN ----------------
// wave per dst node; lane holds VPT contiguous features (vector loads)
template <int VPT>
__global__ __launch_bounds__(256) void k_gcn_fused(
    const float* __restrict__ h, const float* __restrict__ dinv,
    const int* __restrict__ rowptr, const int* __restrict__ csr_src,
    const float* __restrict__ bias, const float* __restrict__ g,
    const float* __restrict__ b, const float* __restrict__ m,
    const float* __restrict__ vv, float* __restrict__ out, int n, int F) {
  using V = typename VecT<VPT>::type;
  int wid = (blockIdx.x * blockDim.x + threadIdx.x) >> 6;
  int lane = threadIdx.x & 63;
  if (wid >= n) return;
  const int fo = lane * VPT;
  float dd = dinv[wid];
  V acc = *(const V*)(h + (size_t)wid * F + fo) * (dd * dd) + *(const V*)(bias + fo);
  int e0 = rowptr[wid], e1 = rowptr[wid + 1];
  for (int e = e0; e < e1; e++) {
    int s = csr_src[e];
    float w = dinv[s] * dd;
    acc += *(const V*)(h + (size_t)s * F + fo) * w;
  }
  V mg = *(const V*)(m + fo);
  V vg = *(const V*)(vv + fo);
  V gg = *(const V*)(g + fo);
  V bg = *(const V*)(b + fo);
  V res;
#pragma unroll
  for (int u = 0; u < VPT; u++) {
    float val = fmaxf(acc[u], 0.f);
    res[u] = (val - mg[u]) * rsqrtf(vg[u] + BN_EPS) * gg[u] + bg[u];
  }
  *(V*)(out + (size_t)wid * F + fo) = res;
}

// ---------------- GAT: per-node logits ----------------
__global__ void k_logits1(const float* __restrict__ h, int ldH,
                          const float* __restrict__ a_s, const float* __restrict__ a_d,
                          float* __restrict__ als, float* __restrict__ ald, int n, int C) {
  int wid = (blockIdx.x * blockDim.x + threadIdx.x) >> 6;
  int lane = threadIdx.x & 63;
  if (wid >= n) return;
  const float* hp = h + (size_t)wid * ldH;
  float ss = 0.f, sd = 0.f;
  for (int c = lane; c < C; c += 64) {
    float hv = hp[c];
    ss += hv * a_s[c];
    sd += hv * a_d[c];
  }
#pragma unroll
  for (int off = 32; off > 0; off >>= 1) {
    ss += __shfl_down(ss, off);
    sd += __shfl_down(sd, off);
  }
  if (lane == 0) { als[wid] = ss; ald[wid] = sd; }
}

// ---------------- fused GAT head: softmax-agg + bias + ReLU + BN ----------------
// wave per dst node; two passes over incoming edges (max, then weighted sum)
template <int VPT>
__global__ __launch_bounds__(256) void k_gat_fused(
    const float* __restrict__ h, int ldH,
    const float* __restrict__ als, const float* __restrict__ ald,
    const int* __restrict__ rowptr, const int* __restrict__ csr_src,
    const float* __restrict__ bias, const float* __restrict__ g,
    const float* __restrict__ b, const float* __restrict__ m,
    const float* __restrict__ vv, float* __restrict__ out, int ldO, int col0, int n) {
  using V = typename VecT<VPT>::type;
  int wid = (blockIdx.x * blockDim.x + threadIdx.x) >> 6;
  int lane = threadIdx.x & 63;
  if (wid >= n) return;
  const int co = lane * VPT;
  float aldd = ald[wid];
  float self_lg = lrelu(als[wid] + aldd);
  int e0 = rowptr[wid], e1 = rowptr[wid + 1];
  float mx = self_lg;
  for (int e = e0; e < e1; e++) {
    mx = fmaxf(mx, lrelu(als[csr_src[e]] + aldd));
  }
  float den = __expf(self_lg - mx);
  V acc = *(const V*)(h + (size_t)wid * ldH + co) * den;
  for (int e = e0; e < e1; e++) {
    int s = csr_src[e];
    float w = __expf(lrelu(als[s] + aldd) - mx);
    den += w;
    acc += *(const V*)(h + (size_t)s * ldH + co) * w;
  }
  float rden = 1.f / den;
  const int fo = col0 + co;
  V bi = *(const V*)(bias + fo);
  V mg = *(const V*)(m + fo);
  V vg = *(const V*)(vv + fo);
  V gg = *(const V*)(g + fo);
  V bg = *(const V*)(b + fo);
  V res;
#pragma unroll
  for (int u = 0; u < VPT; u++) {
    float val = fmaxf(acc[u] * rden + bi[u], 0.f);
    res[u] = (val - mg[u]) * rsqrtf(vg[u] + BN_EPS) * gg[u] + bg[u];
  }
  *(V*)(out + (size_t)wid * ldO + fo) = res;
}

// ---------------- pooling & final FC ----------------
__global__ void k_pool_add(float* __restrict__ pooled, const float* __restrict__ act,
                           const int* __restrict__ batch, int n, int F, int off) {
  long long idx = (long long)blockIdx.x * blockDim.x + threadIdx.x;
  if (idx >= (long long)n * F) return;
  int node = (int)(idx / F);
  int f = (int)(idx % F);
  atomAddF(&pooled[(size_t)batch[node] * 512 + off + f], act[idx]);
}
__global__ void k_fc3(const float* __restrict__ in, const float* __restrict__ w,
                      const float* __restrict__ b, float* __restrict__ out, int g) {
  int wid = (blockIdx.x * blockDim.x + threadIdx.x) >> 6;
  int lane = threadIdx.x & 63;
  if (wid >= g) return;
  float v = in[wid * 64 + lane] * w[lane];
#pragma unroll
  for (int off = 32; off > 0; off >>= 1) v += __shfl_down(v, off);
  if (lane == 0) out[wid] = fmaxf(v + b[0], 0.f);
}

// ---------------- host side ----------------
static void gemm_fp32(hipStream_t s, const float* A, const float* W, const float* bias,
                      float* C, int M, int K, int Nsub, int ldW, int ldC, int col0, int flags) {
  dim3 grid(cdiv(Nsub, 64), cdiv(M, 64));
  k_gemm<<<grid, 256, 0, s>>>(A, W, bias, C, M, K, Nsub, ldW, ldC, col0, flags);
}

static void gemm_mfma(hipStream_t s, const float* A, int lda, int amode,
                      const float* W, int ldW, int wcol0, int K, int Kpad,
                      unsigned* Wt, float* C, int M, int Nsub, int ldC, int ccol0) {
  dim3 wg(cdiv(Nsub, 256), Kpad);
  k_buildwt<<<wg, 256, 0, s>>>(W, ldW, wcol0, Nsub, K, Kpad, Wt);
  dim3 grid(Nsub / 128, cdiv(M, 128));
  k_mfma_gemm<<<grid, 256, 0, s>>>(A, lda, amode, K, Wt, Kpad, C, M, ldC, ccol0);
}

extern "C" void kernel_launch(void* const* d_in, const int* in_sizes, int n_in,
                              void* d_out, int out_size, void* d_ws, size_t ws_size,
                              hipStream_t stream) {
  const float* x = (const float*)d_in[0];
  const int* ei = (const int*)d_in[1];
  const int* batch = (const int*)d_in[2];
  const float* gw1 = (const float*)d_in[3];  const float* gb1 = (const float*)d_in[4];
  const float* gw2 = (const float*)d_in[5];  const float* gb2 = (const float*)d_in[6];
  const float* gw3 = (const float*)d_in[7];  const float* gb3 = (const float*)d_in[8];
  const float* g01g = (const float*)d_in[9];  const float* g01b = (const float*)d_in[10];
  const float* g01m = (const float*)d_in[11]; const float* g01v = (const float*)d_in[12];
  const float* g02g = (const float*)d_in[13]; const float* g02b = (const float*)d_in[14];
  const float* g02m = (const float*)d_in[15]; const float* g02v = (const float*)d_in[16];
  const float* g03g = (const float*)d_in[17]; const float* g03b = (const float*)d_in[18];
  const float* g03m = (const float*)d_in[19]; const float* g03v = (const float*)d_in[20];
  const float* g11g = (const float*)d_in[21]; const float* g11b = (const float*)d_in[22];
  const float* g11m = (const float*)d_in[23]; const float* g11v = (const float*)d_in[24];
  const float* g12g = (const float*)d_in[25]; const float* g12b = (const float*)d_in[26];
  const float* g12m = (const float*)d_in[27]; const float* g12v = (const float*)d_in[28];
  const float* g13g = (const float*)d_in[29]; const float* g13b = (const float*)d_in[30];
  const float* g13m = (const float*)d_in[31]; const float* g13v = (const float*)d_in[32];
  const float* aw1 = (const float*)d_in[33]; const float* as1 = (const float*)d_in[34];
  const float* ad1 = (const float*)d_in[35]; const float* ab1 = (const float*)d_in[36];
  const float* aw2 = (const float*)d_in[37]; const float* as2 = (const float*)d_in[38];
  const float* ad2 = (const float*)d_in[39]; const float* ab2 = (const float*)d_in[40];
  const float* aw3 = (const float*)d_in[41]; const float* as3 = (const float*)d_in[42];
  const float* ad3 = (const float*)d_in[43]; const float* ab3 = (const float*)d_in[44];
  const float* f1w = (const float*)d_in[45]; const float* f1b = (const float*)d_in[46];
  const float* f2w = (const float*)d_in[47]; const float* f2b = (const float*)d_in[48];
  const float* f3w = (const float*)d_in[49]; const float* f3b = (const float*)d_in[50];

  const int* src = ei;
  const int* dst = ei + N_EDGES;

  // ---- workspace carve (well under round-2's proven 239.456 MB) ----
  size_t need = 0;
  need += (size_t)N_NODES * 768;   // OUT
  need += (size_t)N_NODES * 384;   // H
  need += (size_t)N_NODES * 3;     // dinv, als, ald
  need += (size_t)N_NODES * 3 + 1; // degi, rowptr(N+1), cursor
  need += (size_t)N_EDGES;         // csr_src
  need += (size_t)N_GRAPHS * (512 + 256 + 64);  // pooled + fc1/fc2 (Wt aliases fc)
  if (ws_size < need * sizeof(float)) return;  // clean-fail guard

  float* wp = (float*)d_ws;
  float* OUT = wp;     wp += (size_t)N_NODES * 768;
  float* H = wp;       wp += (size_t)N_NODES * 384;
  float* dinv = wp;    wp += N_NODES;
  float* als = wp;     wp += N_NODES;
  float* ald = wp;     wp += N_NODES;
  int* degi = (int*)wp;    wp += N_NODES;
  int* rowptr = (int*)wp;  wp += N_NODES + 1;
  int* cursor = (int*)wp;  wp += N_NODES;
  int* csr_src = (int*)wp; wp += N_EDGES;
  float* pooled = wp; wp += (size_t)N_GRAPHS * 512;
  float* fc1 = wp;    wp += (size_t)N_GRAPHS * 256;
  float* fc2 = wp;    wp += (size_t)N_GRAPHS * 64;
  // Wt (max 384*768 u32 = 294912 words) aliases fc1+fc2 (640000 words);
  // last Wt use (GAT3 GEMM) precedes first fc write in stream order.
  unsigned* Wt = (unsigned*)fc1;

  // ---- CSR build (once, reused by all 12 aggregations) ----
  k_zero_i<<<cdiv(N_NODES, 256), 256, 0, stream>>>(degi, N_NODES);
  k_deg<<<cdiv(N_EDGES, 256), 256, 0, stream>>>(degi, dst, N_EDGES);
  k_dinv<<<cdiv(N_NODES, 256), 256, 0, stream>>>(degi, dinv, N_NODES);
  k_scan<<<1, 1024, 0, stream>>>(degi, rowptr, cursor, N_NODES);
  k_csr_scatter<<<cdiv(N_EDGES, 256), 256, 0, stream>>>(src, dst, rowptr, cursor, csr_src, N_EDGES);
  k_zero<<<cdiv((long long)N_GRAPHS * 512, 256), 256, 0, stream>>>(pooled, (long long)N_GRAPHS * 512);

  const int nodeWaveGrid = cdiv((long long)N_NODES * 64, 256);

  // ---- GCN path ----
  struct { const float *w, *bias, *g, *b, *m, *v; int F; } gcn[3] = {
    {gw1, gb1, g01g, g01b, g01m, g01v, 256},
    {gw2, gb2, g02g, g02b, g02m, g02v, 128},
    {gw3, gb3, g03g, g03b, g03m, g03v, 128}};
  int gF = F_IN;
  for (int l = 0; l < 3; l++) {
    int F = gcn[l].F;
    if (l == 0)
      gemm_mfma(stream, x, F_IN, 0, gcn[l].w, F, 0, F_IN, 384, Wt, H, N_NODES, F, F, 0);
    else
      gemm_mfma(stream, OUT, gF, 2, gcn[l].w, F, 0, gF, gF, Wt, H, N_NODES, F, F, 0);
    if (F == 256)
      k_gcn_fused<4><<<nodeWaveGrid, 256, 0, stream>>>(H, dinv, rowptr, csr_src,
          gcn[l].bias, gcn[l].g, gcn[l].b, gcn[l].m, gcn[l].v, OUT, N_NODES, F);
    else
      k_gcn_fused<2><<<nodeWaveGrid, 256, 0, stream>>>(H, dinv, rowptr, csr_src,
          gcn[l].bias, gcn[l].g, gcn[l].b, gcn[l].m, gcn[l].v, OUT, N_NODES, F);
    gF = F;
  }
  k_pool_add<<<cdiv((long long)N_NODES * 128, 256), 256, 0, stream>>>(pooled, OUT, batch, N_NODES, 128, 0);

  // ---- GAT1: input x, C=256, per-head GEMM into H then fused agg ----
  {
    int C = 256, HC = 768;
    for (int hh = 0; hh < 3; hh++) {
      gemm_mfma(stream, x, F_IN, 0, aw1, HC, hh * C, F_IN, 384, Wt, H, N_NODES, C, C, 0);
      k_logits1<<<nodeWaveGrid, 256, 0, stream>>>(H, C, as1 + hh * C, ad1 + hh * C, als, ald, N_NODES, C);
      k_gat_fused<4><<<nodeWaveGrid, 256, 0, stream>>>(H, C, als, ald, rowptr, csr_src,
          ab1, g11g, g11b, g11m, g11v, OUT, HC, hh * C, N_NODES);
    }
  }

  // ---- GAT2 & GAT3: full GEMM into H, per-head fused agg ----
  struct { const float *w, *s, *d, *bias, *g, *b, *m, *v; int K; } gat[2] = {
    {aw2, as2, ad2, ab2, g12g, g12b, g12m, g12v, 768},
    {aw3, as3, ad3, ab3, g13g, g13b, g13m, g13v, 384}};
  for (int l = 0; l < 2; l++) {
    int C = 128, HC = 384;
    gemm_mfma(stream, OUT, gat[l].K, 2, gat[l].w, HC, 0, gat[l].K, gat[l].K, Wt, H, N_NODES, HC, HC, 0);
    for (int hh = 0; hh < 3; hh++) {
      k_logits1<<<nodeWaveGrid, 256, 0, stream>>>(H + hh * C, HC, gat[l].s + hh * C, gat[l].d + hh * C, als, ald, N_NODES, C);
      k_gat_fused<2><<<nodeWaveGrid, 256, 0, stream>>>(H + hh * C, HC, als, ald, rowptr, csr_src,
          gat[l].bias, gat[l].g, gat[l].b, gat[l].m, gat[l].v, OUT, HC, hh * C, N_NODES);
    }
  }
  k_pool_add<<<cdiv((long long)N_NODES * 384, 256), 256, 0, stream>>>(pooled, OUT, batch, N_NODES, 384, 128);

  // ---- FC head ----
  gemm_fp32(stream, pooled, f1w, f1b, fc1, N_GRAPHS, 512, 256, 256, 256, 0, 3);
  gemm_fp32(stream, fc1, f2w, f2b, fc2, N_GRAPHS, 256, 64, 64, 64, 0, 3);
  k_fc3<<<cdiv((long long)N_GRAPHS * 64, 256), 256, 0, stream>>>(fc2, f3w, f3b, (float*)d_out, N_GRAPHS);
}

// Round 6
// 1732.315 us; speedup vs baseline: 2.7714x; 1.1707x over previous
//
#include <hip/hip_runtime.h>
#include <cstdint>
#include <cstddef>

#define N_NODES 50000
#define N_EDGES 200000
#define N_GRAPHS 2000
#define F_IN 373
#define NEG_SLOPE 0.2f
#define BN_EPS 1e-5f

typedef float f32x4 __attribute__((ext_vector_type(4)));
typedef float f32x2 __attribute__((ext_vector_type(2)));
typedef short s16x8 __attribute__((ext_vector_type(8)));
typedef short s16x4 __attribute__((ext_vector_type(4)));
typedef unsigned int u32x4 __attribute__((ext_vector_type(4)));

template <int VPT> struct VecT;
template <> struct VecT<2> { using type = f32x2; };
template <> struct VecT<4> { using type = f32x4; };

static inline int cdiv(long long a, long long b) { return (int)((a + b - 1) / b); }

__device__ __forceinline__ float lrelu(float x) { return x > 0.f ? x : NEG_SLOPE * x; }

__device__ __forceinline__ void atomAddF(float* p, float v) {
#if defined(__HIP_DEVICE_COMPILE__)
  unsafeAtomicAdd(p, v);
#else
  atomicAdd(p, v);
#endif
}

// RNE bf16 + hi/lo split: hi = bf16(f), lo = bf16(f - hi)
__device__ __forceinline__ unsigned short bf16rne(float f) {
  unsigned u = __float_as_uint(f);
  unsigned r = u + 0x7fffu + ((u >> 16) & 1u);
  return (unsigned short)(r >> 16);
}
__device__ __forceinline__ void split2(float f, unsigned short& hi, unsigned short& lo) {
  hi = bf16rne(f);
  float fh = __uint_as_float(((unsigned)hi) << 16);
  lo = bf16rne(f - fh);
}
__device__ __forceinline__ unsigned packsplit(float f) {
  unsigned short hi, lo;
  split2(f, hi, lo);
  return (((unsigned)hi) << 16) | (unsigned)lo;
}

// swizzled LDS address (in shorts) for tile element (row, k); k-tile = 32
// XOR of k-octet into row-low-bits breaks staging-write bank conflicts.
__device__ __forceinline__ int swz(int row, int k) {
  return ((row >> 4) << 9) | ((k >> 3) << 7) | ((((row & 15) ^ (k >> 3))) << 3) | (k & 7);
}

// ---------------- utility ----------------
__global__ void k_zero(float* p, long long n) {
  long long i = (long long)blockIdx.x * blockDim.x + threadIdx.x;
  if (i < n) p[i] = 0.f;
}
__global__ void k_zero_i(int* p, int n) {
  int i = blockIdx.x * blockDim.x + threadIdx.x;
  if (i < n) p[i] = 0;
}
__global__ void k_deg(int* __restrict__ deg, const int* __restrict__ dst, int e) {
  int i = blockIdx.x * blockDim.x + threadIdx.x;
  if (i < e) atomicAdd(&deg[dst[i]], 1);
}
__global__ void k_dinv(const int* __restrict__ deg, float* __restrict__ dinv, int n) {
  int i = blockIdx.x * blockDim.x + threadIdx.x;
  if (i < n) dinv[i] = rsqrtf((float)deg[i] + 1.0f);
}

// single-block exclusive scan of deg -> rowptr[0..n], zeroes cursor
__global__ void k_scan(const int* __restrict__ deg, int* __restrict__ rowptr,
                       int* __restrict__ cursor, int n) {
  __shared__ int wsum[16];
  __shared__ int carry_s;
  const int lane = threadIdx.x & 63;
  const int wid = threadIdx.x >> 6;
  if (threadIdx.x == 0) carry_s = 0;
  __syncthreads();
  for (int base = 0; base < n; base += 1024) {
    int i = base + threadIdx.x;
    int v = (i < n) ? deg[i] : 0;
    int s = v;
#pragma unroll
    for (int off = 1; off < 64; off <<= 1) {
      int t = __shfl_up(s, off);
      if (lane >= off) s += t;
    }
    if (lane == 63) wsum[wid] = s;
    __syncthreads();
    if (threadIdx.x == 0) {
      int acc = carry_s;
#pragma unroll
      for (int w = 0; w < 16; w++) { int t = wsum[w]; wsum[w] = acc; acc += t; }
      carry_s = acc;
    }
    __syncthreads();
    if (i < n) { rowptr[i] = wsum[wid] + s - v; cursor[i] = 0; }
    __syncthreads();
  }
  if (threadIdx.x == 0) rowptr[n] = carry_s;
}

__global__ void k_csr_scatter(const int* __restrict__ src, const int* __restrict__ dst,
                              const int* __restrict__ rowptr, int* __restrict__ cursor,
                              int* __restrict__ csr_src, int e) {
  int i = blockIdx.x * blockDim.x + threadIdx.x;
  if (i >= e) return;
  int d = dst[i];
  int pos = rowptr[d] + atomicAdd(&cursor[d], 1);
  csr_src[pos] = src[i];
}

// build Wt[n, k] packed-split from W[k, col0+n], k < K (zero pad to Kpad)
__global__ void k_buildwt(const float* __restrict__ W, int ldW, int col0, int Nsub,
                          int K, int Kpad, unsigned* __restrict__ Wt) {
  int n = blockIdx.x * blockDim.x + threadIdx.x;
  int k = blockIdx.y;
  if (n >= Nsub) return;
  float v = (k < K) ? W[(size_t)k * ldW + col0 + n] : 0.f;
  Wt[(size_t)n * Kpad + k] = packsplit(v);
}

// ---------------- MFMA split-bf16 GEMM, 64x128 tile, coalesced staging ----------------
// C[M, Nsub] (ld=ldC, col offset col0) = A[M, K] @ Wt^T   (Wt: [Nsub, Kpad])
// amode: 0 = fp32 scalar coalesced loads w/ k<Kact guard; 2 = fp32 float4 loads.
// If a_s != null: fuse attention logits — atomicAdd per-row h.a_s / h.a_d into
// als/ald at [head*N_NODES + row], head = bn >> lshift (col-blocks align w/ heads).
__global__ __launch_bounds__(256) void k_mfma_gemm(
    const float* __restrict__ Ap, int lda, int amode, int Kact,
    const unsigned* __restrict__ Wt, int Kpad,
    float* __restrict__ C, int M, int ldC, int col0,
    const float* __restrict__ a_s, const float* __restrict__ a_d,
    float* __restrict__ als, float* __restrict__ ald, int lshift) {
  __shared__ unsigned short Ah[64 * 32], Al[64 * 32], Bh[128 * 32], Bl[128 * 32];
  const int bm = blockIdx.y * 64;
  const int bn = blockIdx.x * 128;
  const int tid = threadIdx.x;
  const int lane = tid & 63;
  const int wave = tid >> 6;
  const int wm = wave & 1;   // row half (32 rows)
  const int wn = wave >> 1;  // col half (64 cols)

  f32x4 acc[2][4];
#pragma unroll
  for (int i = 0; i < 2; i++)
#pragma unroll
    for (int j = 0; j < 4; j++) acc[i][j] = (f32x4){0.f, 0.f, 0.f, 0.f};

  const int srow = tid >> 3;        // 0..31
  const int skq = (tid & 7) << 2;   // 0,4,...,28

  for (int k0 = 0; k0 < Kpad; k0 += 32) {
    // ---- stage A: 64 rows, 8 lanes sweep 32 contiguous k per row ----
#pragma unroll
    for (int i = 0; i < 2; i++) {
      int row = i * 32 + srow;
      int grow = bm + row;
      unsigned short hv[4], lv[4];
      if (amode == 2) {
        f32x4 v = (grow < M) ? *(const f32x4*)(Ap + (size_t)grow * lda + k0 + skq)
                             : (f32x4){0.f, 0.f, 0.f, 0.f};
#pragma unroll
        for (int u = 0; u < 4; u++) split2(v[u], hv[u], lv[u]);
      } else {
        const float* ap = Ap + (size_t)grow * lda;
#pragma unroll
        for (int u = 0; u < 4; u++) {
          int kc = k0 + skq + u;
          float f = (grow < M && kc < Kact) ? ap[kc] : 0.f;
          split2(f, hv[u], lv[u]);
        }
      }
      int eb = swz(row, skq);
      *(s16x4*)&Ah[eb] = *(s16x4*)hv;
      *(s16x4*)&Al[eb] = *(s16x4*)lv;
    }
    // ---- stage B: 128 Wt rows ----
#pragma unroll
    for (int i = 0; i < 4; i++) {
      int row = i * 32 + srow;
      u32x4 v = *(const u32x4*)(Wt + (size_t)(bn + row) * Kpad + k0 + skq);
      unsigned short hv[4], lv[4];
#pragma unroll
      for (int u = 0; u < 4; u++) { hv[u] = (unsigned short)(v[u] >> 16); lv[u] = (unsigned short)(v[u] & 0xffffu); }
      int eb = swz(row, skq);
      *(s16x4*)&Bh[eb] = *(s16x4*)hv;
      *(s16x4*)&Bl[eb] = *(s16x4*)lv;
    }
    __syncthreads();
    // ---- compute: 24 MFMAs / wave / k-tile ----
    const int koct = lane >> 4;
    const int mrow = lane & 15;
    const int fo = (koct << 7) + (((mrow ^ koct)) << 3);
    s16x8 ah[2], al[2];
#pragma unroll
    for (int g = 0; g < 2; g++) {
      int ab = ((wm * 2 + g) << 9) + fo;
      ah[g] = *(const s16x8*)&Ah[ab];
      al[g] = *(const s16x8*)&Al[ab];
    }
#pragma unroll
    for (int j = 0; j < 4; j++) {
      int bb = ((wn * 4 + j) << 9) + fo;
      s16x8 bhj = *(const s16x8*)&Bh[bb];
      s16x8 blj = *(const s16x8*)&Bl[bb];
#pragma unroll
      for (int g = 0; g < 2; g++) {
        acc[g][j] = __builtin_amdgcn_mfma_f32_16x16x32_bf16(ah[g], bhj, acc[g][j], 0, 0, 0);
        acc[g][j] = __builtin_amdgcn_mfma_f32_16x16x32_bf16(al[g], bhj, acc[g][j], 0, 0, 0);
        acc[g][j] = __builtin_amdgcn_mfma_f32_16x16x32_bf16(ah[g], blj, acc[g][j], 0, 0, 0);
      }
    }
    __syncthreads();
  }
  // ---- epilogue: C write (+ optional fused logits) ----
  const int mrow = lane & 15;
  const int rq = (lane >> 4) << 2;
  float asv[4], adv[4];
  if (a_s) {
#pragma unroll
    for (int j = 0; j < 4; j++) {
      int c = bn + wn * 64 + j * 16 + mrow;
      asv[j] = a_s[c];
      adv[j] = a_d[c];
    }
  }
  const int head = bn >> lshift;
#pragma unroll
  for (int g = 0; g < 2; g++) {
#pragma unroll
    for (int r = 0; r < 4; r++) {
      int row = bm + wm * 32 + g * 16 + rq + r;
      bool rok = row < M;
      float ps = 0.f, pd = 0.f;
#pragma unroll
      for (int j = 0; j < 4; j++) {
        int ccol = bn + wn * 64 + j * 16 + mrow;
        float v = acc[g][j][r];
        if (rok) C[(size_t)row * ldC + col0 + ccol] = v;
        ps += v * asv[j];
        pd += v * adv[j];
      }
      if (a_s) {
#pragma unroll
        for (int off = 1; off < 16; off <<= 1) {
          ps += __shfl_xor(ps, off);
          pd += __shfl_xor(pd, off);
        }
        if (mrow == 0 && rok) {
          atomAddF(&als[(size_t)head * N_NODES + row], ps);
          atomAddF(&ald[(size_t)head * N_NODES + row], pd);
        }
      }
    }
  }
}

// -------- small fp32 GEMM (FC head only) --------
__global__ __launch_bounds__(256) void k_gemm(
    const float* __restrict__ A, const float* __restrict__ W,
    const float* __restrict__ bias, float* __restrict__ C,
    int M, int K, int Nsub, int ldW, int ldC, int col0, int flags) {
  __shared__ float As[16][68];
  __shared__ float Bs[16][68];
  const int bm = blockIdx.y * 64;
  const int bn = blockIdx.x * 64;
  const int tid = threadIdx.x;
  const int tm = (tid >> 4) << 2;
  const int tn = (tid & 15) << 2;
  float acc[4][4] = {};
  for (int k0 = 0; k0 < K; k0 += 16) {
    {
      int idx = tid * 4;
      int row = idx >> 4;
      int kk = idx & 15;
      const float* ap = A + (size_t)(bm + row) * K + k0 + kk;
      bool rok = (bm + row) < M;
#pragma unroll
      for (int i = 0; i < 4; i++) {
        int kcur = k0 + kk + i;
        As[kk + i][row] = (rok && kcur < K) ? ap[i] : 0.f;
      }
    }
#pragma unroll
    for (int i = 0; i < 4; i++) {
      int idx = tid + i * 256;
      int kk = idx >> 6;
      int nn = idx & 63;
      int kcur = k0 + kk;
      Bs[kk][nn] = (kcur < K && (bn + nn) < Nsub)
                       ? W[(size_t)kcur * ldW + col0 + bn + nn] : 0.f;
    }
    __syncthreads();
#pragma unroll
    for (int kk = 0; kk < 16; kk++) {
      float av[4], bv[4];
#pragma unroll
      for (int i = 0; i < 4; i++) av[i] = As[kk][tm + i];
#pragma unroll
      for (int j = 0; j < 4; j++) bv[j] = Bs[kk][tn + j];
#pragma unroll
      for (int i = 0; i < 4; i++)
#pragma unroll
        for (int j = 0; j < 4; j++) acc[i][j] += av[i] * bv[j];
    }
    __syncthreads();
  }
#pragma unroll
  for (int i = 0; i < 4; i++) {
    int row = bm + tm + i;
    if (row >= M) continue;
#pragma unroll
    for (int j = 0; j < 4; j++) {
      int col = bn + tn + j;
      if (col >= Nsub) continue;
      float v = acc[i][j];
      if (flags & 1) v += bias[col0 + col];
      if (flags & 2) v = fmaxf(v, 0.f);
      C[(size_t)row * ldC + col] = v;
    }
  }
}

// ---------------- fused GCN aggregation + ReLU + BN ----------------
template <int VPT>
__global__ __launch_bounds__(256) void k_gcn_fused(
    const float* __restrict__ h, const float* __restrict__ dinv,
    const int* __restrict__ rowptr, const int* __restrict__ csr_src,
    const float* __restrict__ bias, const float* __restrict__ g,
    const float* __restrict__ b, const float* __restrict__ m,
    const float* __restrict__ vv, float* __restrict__ out, int n, int F) {
  using V = typename VecT<VPT>::type;
  int wid = (blockIdx.x * blockDim.x + threadIdx.x) >> 6;
  int lane = threadIdx.x & 63;
  if (wid >= n) return;
  const int fo = lane * VPT;
  float dd = dinv[wid];
  V acc = *(const V*)(h + (size_t)wid * F + fo) * (dd * dd) + *(const V*)(bias + fo);
  int e0 = rowptr[wid], e1 = rowptr[wid + 1];
  for (int e = e0; e < e1; e++) {
    int s = csr_src[e];
    float w = dinv[s] * dd;
    acc += *(const V*)(h + (size_t)s * F + fo) * w;
  }
  V mg = *(const V*)(m + fo);
  V vg = *(const V*)(vv + fo);
  V gg = *(const V*)(g + fo);
  V bg = *(const V*)(b + fo);
  V res;
#pragma unroll
  for (int u = 0; u < VPT; u++) {
    float val = fmaxf(acc[u], 0.f);
    res[u] = (val - mg[u]) * rsqrtf(vg[u] + BN_EPS) * gg[u] + bg[u];
  }
  *(V*)(out + (size_t)wid * F + fo) = res;
}

// ---------------- fused GAT head: softmax-agg + bias + ReLU + BN ----------------
template <int VPT>
__global__ __launch_bounds__(256) void k_gat_fused(
    const float* __restrict__ h, int ldH,
    const float* __restrict__ als, const float* __restrict__ ald,
    const int* __restrict__ rowptr, const int* __restrict__ csr_src,
    const float* __restrict__ bias, const float* __restrict__ g,
    const float* __restrict__ b, const float* __restrict__ m,
    const float* __restrict__ vv, float* __restrict__ out, int ldO, int col0, int n) {
  using V = typename VecT<VPT>::type;
  int wid = (blockIdx.x * blockDim.x + threadIdx.x) >> 6;
  int lane = threadIdx.x & 63;
  if (wid >= n) return;
  const int co = lane * VPT;
  float aldd = ald[wid];
  float self_lg = lrelu(als[wid] + aldd);
  int e0 = rowptr[wid], e1 = rowptr[wid + 1];
  float mx = self_lg;
  for (int e = e0; e < e1; e++) {
    mx = fmaxf(mx, lrelu(als[csr_src[e]] + aldd));
  }
  float den = __expf(self_lg - mx);
  V acc = *(const V*)(h + (size_t)wid * ldH + co) * den;
  for (int e = e0; e < e1; e++) {
    int s = csr_src[e];
    float w = __expf(lrelu(als[s] + aldd) - mx);
    den += w;
    acc += *(const V*)(h + (size_t)s * ldH + co) * w;
  }
  float rden = 1.f / den;
  const int fo = col0 + co;
  V bi = *(const V*)(bias + fo);
  V mg = *(const V*)(m + fo);
  V vg = *(const V*)(vv + fo);
  V gg = *(const V*)(g + fo);
  V bg = *(const V*)(b + fo);
  V res;
#pragma unroll
  for (int u = 0; u < VPT; u++) {
    float val = fmaxf(acc[u] * rden + bi[u], 0.f);
    res[u] = (val - mg[u]) * rsqrtf(vg[u] + BN_EPS) * gg[u] + bg[u];
  }
  *(V*)(out + (size_t)wid * ldO + fo) = res;
}

// ---------------- pooling & final FC ----------------
__global__ void k_pool_add(float* __restrict__ pooled, const float* __restrict__ act,
                           const int* __restrict__ batch, int n, int F, int off) {
  long long idx = (long long)blockIdx.x * blockDim.x + threadIdx.x;
  if (idx >= (long long)n * F) return;
  int node = (int)(idx / F);
  int f = (int)(idx % F);
  atomAddF(&pooled[(size_t)batch[node] * 512 + off + f], act[idx]);
}
__global__ void k_fc3(const float* __restrict__ in, const float* __restrict__ w,
                      const float* __restrict__ b, float* __restrict__ out, int g) {
  int wid = (blockIdx.x * blockDim.x + threadIdx.x) >> 6;
  int lane = threadIdx.x & 63;
  if (wid >= g) return;
  float v = in[wid * 64 + lane] * w[lane];
#pragma unroll
  for (int off = 32; off > 0; off >>= 1) v += __shfl_down(v, off);
  if (lane == 0) out[wid] = fmaxf(v + b[0], 0.f);
}

// ---------------- host side ----------------
static void gemm_fp32(hipStream_t s, const float* A, const float* W, const float* bias,
                      float* C, int M, int K, int Nsub, int ldW, int ldC, int col0, int flags) {
  dim3 grid(cdiv(Nsub, 64), cdiv(M, 64));
  k_gemm<<<grid, 256, 0, s>>>(A, W, bias, C, M, K, Nsub, ldW, ldC, col0, flags);
}

static void gemm_mfma(hipStream_t s, const float* A, int lda, int amode,
                      const float* W, int ldW, int wcol0, int K, int Kpad,
                      unsigned* Wt, float* C, int M, int Nsub, int ldC, int ccol0,
                      const float* a_s = nullptr, const float* a_d = nullptr,
                      float* als = nullptr, float* ald = nullptr, int lshift = 30) {
  dim3 wg(cdiv(Nsub, 256), Kpad);
  k_buildwt<<<wg, 256, 0, s>>>(W, ldW, wcol0, Nsub, K, Kpad, Wt);
  dim3 grid(Nsub / 128, cdiv(M, 64));
  k_mfma_gemm<<<grid, 256, 0, s>>>(A, lda, amode, K, Wt, Kpad, C, M, ldC, ccol0,
                                   a_s, a_d, als, ald, lshift);
}

extern "C" void kernel_launch(void* const* d_in, const int* in_sizes, int n_in,
                              void* d_out, int out_size, void* d_ws, size_t ws_size,
                              hipStream_t stream) {
  const float* x = (const float*)d_in[0];
  const int* ei = (const int*)d_in[1];
  const int* batch = (const int*)d_in[2];
  const float* gw1 = (const float*)d_in[3];  const float* gb1 = (const float*)d_in[4];
  const float* gw2 = (const float*)d_in[5];  const float* gb2 = (const float*)d_in[6];
  const float* gw3 = (const float*)d_in[7];  const float* gb3 = (const float*)d_in[8];
  const float* g01g = (const float*)d_in[9];  const float* g01b = (const float*)d_in[10];
  const float* g01m = (const float*)d_in[11]; const float* g01v = (const float*)d_in[12];
  const float* g02g = (const float*)d_in[13]; const float* g02b = (const float*)d_in[14];
  const float* g02m = (const float*)d_in[15]; const float* g02v = (const float*)d_in[16];
  const float* g03g = (const float*)d_in[17]; const float* g03b = (const float*)d_in[18];
  const float* g03m = (const float*)d_in[19]; const float* g03v = (const float*)d_in[20];
  const float* g11g = (const float*)d_in[21]; const float* g11b = (const float*)d_in[22];
  const float* g11m = (const float*)d_in[23]; const float* g11v = (const float*)d_in[24];
  const float* g12g = (const float*)d_in[25]; const float* g12b = (const float*)d_in[26];
  const float* g12m = (const float*)d_in[27]; const float* g12v = (const float*)d_in[28];
  const float* g13g = (const float*)d_in[29]; const float* g13b = (const float*)d_in[30];
  const float* g13m = (const float*)d_in[31]; const float* g13v = (const float*)d_in[32];
  const float* aw1 = (const float*)d_in[33]; const float* as1 = (const float*)d_in[34];
  const float* ad1 = (const float*)d_in[35]; const float* ab1 = (const float*)d_in[36];
  const float* aw2 = (const float*)d_in[37]; const float* as2 = (const float*)d_in[38];
  const float* ad2 = (const float*)d_in[39]; const float* ad2b = nullptr;
  const float* ab2 = (const float*)d_in[40];
  const float* aw3 = (const float*)d_in[41]; const float* as3 = (const float*)d_in[42];
  const float* ad3 = (const float*)d_in[43]; const float* ab3 = (const float*)d_in[44];
  const float* f1w = (const float*)d_in[45]; const float* f1b = (const float*)d_in[46];
  const float* f2w = (const float*)d_in[47]; const float* f2b = (const float*)d_in[48];
  const float* f3w = (const float*)d_in[49]; const float* f3b = (const float*)d_in[50];
  (void)ad2b;

  const int* src = ei;
  const int* dst = ei + N_EDGES;

  // ---- workspace carve: exactly round-2's proven 239.456 MB ----
  size_t need = 0;
  need += (size_t)N_NODES * 768;   // OUT
  need += (size_t)N_NODES * 384;   // H
  need += (size_t)N_NODES;         // dinv
  need += (size_t)N_NODES * 6;     // als3 + ald3 (head-major; degi/cursor alias here)
  need += (size_t)N_NODES + 1;     // rowptr
  need += (size_t)N_EDGES;         // csr_src
  need += (size_t)N_GRAPHS * (512 + 256 + 64);  // pooled + fc1/fc2 (Wt aliases fc)
  if (ws_size < need * sizeof(float)) return;  // clean-fail guard

  float* wp = (float*)d_ws;
  float* OUT = wp;     wp += (size_t)N_NODES * 768;
  float* H = wp;       wp += (size_t)N_NODES * 384;
  float* dinv = wp;    wp += N_NODES;
  float* als3 = wp;    wp += (size_t)N_NODES * 3;
  float* ald3 = wp;    wp += (size_t)N_NODES * 3;
  int* rowptr = (int*)wp;  wp += N_NODES + 1;
  int* csr_src = (int*)wp; wp += N_EDGES;
  float* pooled = wp; wp += (size_t)N_GRAPHS * 512;
  float* fc1 = wp;    wp += (size_t)N_GRAPHS * 256;
  float* fc2 = wp;    wp += (size_t)N_GRAPHS * 64;
  // aliases: degi/cursor live in als3/ald3 (dead before first als use);
  // Wt (max 384*768 = 294912 u32) aliases fc1+fc2 (640000 words).
  int* degi = (int*)als3;
  int* cursor = (int*)ald3;
  unsigned* Wt = (unsigned*)fc1;

  // ---- CSR build (once) ----
  k_zero_i<<<cdiv(N_NODES, 256), 256, 0, stream>>>(degi, N_NODES);
  k_deg<<<cdiv(N_EDGES, 256), 256, 0, stream>>>(degi, dst, N_EDGES);
  k_dinv<<<cdiv(N_NODES, 256), 256, 0, stream>>>(degi, dinv, N_NODES);
  k_scan<<<1, 1024, 0, stream>>>(degi, rowptr, cursor, N_NODES);
  k_csr_scatter<<<cdiv(N_EDGES, 256), 256, 0, stream>>>(src, dst, rowptr, cursor, csr_src, N_EDGES);
  k_zero<<<cdiv((long long)N_GRAPHS * 512, 256), 256, 0, stream>>>(pooled, (long long)N_GRAPHS * 512);

  const int nodeWaveGrid = cdiv((long long)N_NODES * 64, 256);

  // ---- GCN path ----
  struct { const float *w, *bias, *g, *b, *m, *v; int F; } gcn[3] = {
    {gw1, gb1, g01g, g01b, g01m, g01v, 256},
    {gw2, gb2, g02g, g02b, g02m, g02v, 128},
    {gw3, gb3, g03g, g03b, g03m, g03v, 128}};
  int gF = F_IN;
  for (int l = 0; l < 3; l++) {
    int F = gcn[l].F;
    if (l == 0)
      gemm_mfma(stream, x, F_IN, 0, gcn[l].w, F, 0, F_IN, 384, Wt, H, N_NODES, F, F, 0);
    else
      gemm_mfma(stream, OUT, gF, 2, gcn[l].w, F, 0, gF, gF, Wt, H, N_NODES, F, F, 0);
    if (F == 256)
      k_gcn_fused<4><<<nodeWaveGrid, 256, 0, stream>>>(H, dinv, rowptr, csr_src,
          gcn[l].bias, gcn[l].g, gcn[l].b, gcn[l].m, gcn[l].v, OUT, N_NODES, F);
    else
      k_gcn_fused<2><<<nodeWaveGrid, 256, 0, stream>>>(H, dinv, rowptr, csr_src,
          gcn[l].bias, gcn[l].g, gcn[l].b, gcn[l].m, gcn[l].v, OUT, N_NODES, F);
    gF = F;
  }
  k_pool_add<<<cdiv((long long)N_NODES * 128, 256), 256, 0, stream>>>(pooled, OUT, batch, N_NODES, 128, 0);

  // ---- GAT1: input x, C=256, per-head GEMM (logits fused) + fused agg ----
  {
    int C = 256, HC = 768;
    for (int hh = 0; hh < 3; hh++) {
      k_zero<<<cdiv((long long)N_NODES * 6, 256), 256, 0, stream>>>(als3, (long long)N_NODES * 6);
      gemm_mfma(stream, x, F_IN, 0, aw1, HC, hh * C, F_IN, 384, Wt, H, N_NODES, C, C, 0,
                as1 + hh * C, ad1 + hh * C, als3, ald3, 30);
      k_gat_fused<4><<<nodeWaveGrid, 256, 0, stream>>>(H, C, als3, ald3, rowptr, csr_src,
          ab1, g11g, g11b, g11m, g11v, OUT, HC, hh * C, N_NODES);
    }
  }

  // ---- GAT2 & GAT3: one GEMM (3-head logits fused), per-head fused agg ----
  struct { const float *w, *s, *d, *bias, *g, *b, *m, *v; int K; } gat[2] = {
    {aw2, as2, ad2, ab2, g12g, g12b, g12m, g12v, 768},
    {aw3, as3, ad3, ab3, g13g, g13b, g13m, g13v, 384}};
  for (int l = 0; l < 2; l++) {
    int C = 128, HC = 384;
    k_zero<<<cdiv((long long)N_NODES * 6, 256), 256, 0, stream>>>(als3, (long long)N_NODES * 6);
    gemm_mfma(stream, OUT, gat[l].K, 2, gat[l].w, HC, 0, gat[l].K, gat[l].K, Wt, H, N_NODES, HC, HC, 0,
              gat[l].s, gat[l].d, als3, ald3, 7);
    for (int hh = 0; hh < 3; hh++) {
      k_gat_fused<2><<<nodeWaveGrid, 256, 0, stream>>>(H + hh * C, HC,
          als3 + (size_t)hh * N_NODES, ald3 + (size_t)hh * N_NODES, rowptr, csr_src,
          gat[l].bias, gat[l].g, gat[l].b, gat[l].m, gat[l].v, OUT, HC, hh * C, N_NODES);
    }
  }
  k_pool_add<<<cdiv((long long)N_NODES * 384, 256), 256, 0, stream>>>(pooled, OUT, batch, N_NODES, 384, 128);

  // ---- FC head ----
  gemm_fp32(stream, pooled, f1w, f1b, fc1, N_GRAPHS, 512, 256, 256, 256, 0, 3);
  gemm_fp32(stream, fc1, f2w, f2b, fc2, N_GRAPHS, 256, 64, 64, 64, 0, 3);
  k_fc3<<<cdiv((long long)N_GRAPHS * 64, 256), 256, 0, stream>>>(fc2, f3w, f3b, (float*)d_out, N_GRAPHS);
}